// Round 7
// baseline (301.883 us; speedup 1.0000x reference)
//
#include <hip/hip_runtime.h>
#include <hip/hip_bf16.h>

typedef float f4v __attribute__((ext_vector_type(4)));
typedef short s8v __attribute__((ext_vector_type(8)));
typedef unsigned short u8v __attribute__((ext_vector_type(8)));

__device__ __forceinline__ float bf2f(ushort u) {
  union { unsigned int i; float f; } c; c.i = ((unsigned int)u) << 16;
  return c.f;
}
__device__ __forceinline__ ushort f2bf(float f) {
  union { ushort s; __hip_bfloat16 h; } c; c.h = __float2bfloat16(f);
  return c.s;
}
// Direct global->LDS 16B DMA. lds base must be wave-uniform; lane l writes
// lds + l*16. Source address is per-lane.
__device__ __forceinline__ void gload16(const ushort* g, ushort* l) {
  __builtin_amdgcn_global_load_lds(
      (const __attribute__((address_space(1))) unsigned int*)g,
      (__attribute__((address_space(3))) unsigned int*)l, 16, 0, 0);
}

// ---------------------------------------------------------------------------
// K1 (+prep fold): bx<4096: per (b,c) conv plane work.
// bx in [4096,5120): cast four fp32 q/k weights [o][k] to bf16 hi/lo pairs.
// bx in [5120,5632): cast fc_v|fc_o to bf16 [n][k].
// ---------------------------------------------------------------------------
__global__ __launch_bounds__(256) void k_conv(
    const float* __restrict__ x,
    const float* __restrict__ wqh, const float* __restrict__ bqh,
    const float* __restrict__ wkh, const float* __restrict__ bkh,
    const float* __restrict__ wv,  const float* __restrict__ bv,
    const float* __restrict__ wqw, const float* __restrict__ bqw,
    const float* __restrict__ wkw, const float* __restrict__ bkw,
    const float* __restrict__ fq0, const float* __restrict__ fq1,
    const float* __restrict__ fq2, const float* __restrict__ fq3,
    const float* __restrict__ fwv, const float* __restrict__ fwo,
    ushort* __restrict__ whl, ushort* __restrict__ wbf,
    ushort* __restrict__ convV,
    float* __restrict__ qhm, float* __restrict__ khm,
    float* __restrict__ qwm, float* __restrict__ kwm) {
  __shared__ float xs[68 * 68];
  __shared__ float wl[5][9];
  __shared__ float bl[5];

  int bx = blockIdx.x;
  int tid = threadIdx.x;

  if (bx >= 4096) {
    int pb = bx - 4096;
    if (pb < 1024) {
      int mat = pb >> 8;
      int i = (pb & 255) * 256 + tid;
      const float* p = mat == 0 ? fq0 : mat == 1 ? fq1 : mat == 2 ? fq2 : fq3;
      float f = p[i];
      ushort hi = f2bf(f);
      ushort lo = f2bf(f - bf2f(hi));
      whl[(size_t)mat * 131072 + i] = hi;
      whl[(size_t)mat * 131072 + 65536 + i] = lo;
    } else {
      int idx = (pb - 1024) * 256 + tid;  // 0..131071
      const float* src = (idx >> 16) ? fwo : fwv;
      wbf[idx] = f2bf(src[idx & 65535]);
    }
    return;
  }

  int b = bx >> 8;
  int c = bx & 255;
  int lane = tid & 63, wave = tid >> 6;

  const float* xp = x + (size_t)(b * 256 + c) * 4096;
#pragma unroll
  for (int i = 0; i < 4; i++) {
    int flat = tid + i * 256;          // 0..1023
    int r = flat >> 4, c4 = (flat & 15) * 4;
    float4 v = *(const float4*)(xp + r * 64 + c4);
    *(float4*)&xs[(r + 1) * 68 + 4 + c4] = v;
  }
  if (tid < 72) { xs[tid] = 0.f; xs[65 * 68 + tid] = 0.f; }
  if (tid >= 72 && tid < 200) {
    int t = tid - 72;
    int pr = (t & 63) + 1, side = t >> 6;
    xs[pr * 68 + (side ? 68 : 3)] = 0.f;
  }
  if (tid >= 200 && tid < 245) {
    int t = tid - 200;
    int cw = t / 9, wi = t % 9;
    const float* wp = cw == 0 ? wqh : cw == 1 ? wkh : cw == 2 ? wv
                    : cw == 3 ? wqw : wkw;
    wl[cw][wi] = wp[c * 9 + wi];
  } else if (tid >= 245 && tid < 250) {
    int cw = tid - 245;
    const float* bp = cw == 0 ? bqh : cw == 1 ? bkh : cw == 2 ? bv
                    : cw == 3 ? bqw : bkw;
    bl[cw] = bp[c];
  }
  __syncthreads();

  // ---- v-conv: wave handles rows h0..h0+15, lane = output col ----
  {
    int w = lane;
    int h0 = wave * 16;
    float v0 = wl[2][0], v1 = wl[2][1], v2 = wl[2][2];
    float v3 = wl[2][3], v4 = wl[2][4], v5 = wl[2][5];
    float v6 = wl[2][6], v7 = wl[2][7], v8 = wl[2][8];
    float bvv = bl[2];
    float a00 = xs[h0 * 68 + 3 + w], a01 = xs[h0 * 68 + 4 + w],
          a02 = xs[h0 * 68 + 5 + w];
    float a10 = xs[(h0 + 1) * 68 + 3 + w], a11 = xs[(h0 + 1) * 68 + 4 + w],
          a12 = xs[(h0 + 1) * 68 + 5 + w];
    ushort* cp = convV + (size_t)(b * 256 + c) * 4096 + h0 * 64 + w;
#pragma unroll
    for (int i = 0; i < 16; i++) {
      int pr = h0 + i + 2;
      float a20 = xs[pr * 68 + 3 + w];
      float a21 = xs[pr * 68 + 4 + w];
      float a22 = xs[pr * 68 + 5 + w];
      float acc = bvv;
      acc += a00 * v0 + a01 * v1 + a02 * v2;
      acc += a10 * v3 + a11 * v4 + a12 * v5;
      acc += a20 * v6 + a21 * v7 + a22 * v8;
      cp[i * 64] = f2bf(acc);
      a00 = a10; a01 = a11; a02 = a12;
      a10 = a20; a11 = a21; a12 = a22;
    }
  }

  // ---- pooled means from linearity: wave0 rows, wave1 cols ----
  if (wave == 0) {
    float rs = 0.f, e0 = 0.f, e1 = 0.f;
    const float* rowp = &xs[(lane + 1) * 68 + 4];
#pragma unroll
    for (int i = 0; i < 16; i++) {
      float4 v = *(const float4*)(rowp + i * 4);
      rs += (v.x + v.y) + (v.z + v.w);
      if (i == 0) e0 = v.x;
      if (i == 15) e1 = v.w;
    }
    float rsP = __shfl(rs, lane - 1, 64); rsP = (lane == 0) ? 0.f : rsP;
    float rsN = __shfl(rs, lane + 1, 64); rsN = (lane == 63) ? 0.f : rsN;
    float e0P = __shfl(e0, lane - 1, 64); e0P = (lane == 0) ? 0.f : e0P;
    float e0N = __shfl(e0, lane + 1, 64); e0N = (lane == 63) ? 0.f : e0N;
    float e1P = __shfl(e1, lane - 1, 64); e1P = (lane == 0) ? 0.f : e1P;
    float e1N = __shfl(e1, lane + 1, 64); e1N = (lane == 63) ? 0.f : e1N;
    float RS[3] = {rsP, rs, rsN};
    float E0[3] = {e0P, e0, e0N};
    float E1[3] = {e1P, e1, e1N};
    float vq = 0.f, vk = 0.f;
#pragma unroll
    for (int ky = 0; ky < 3; ky++) {
      vq += (wl[0][ky * 3] + wl[0][ky * 3 + 1] + wl[0][ky * 3 + 2]) * RS[ky]
            - wl[0][ky * 3] * E1[ky] - wl[0][ky * 3 + 2] * E0[ky];
      vk += (wl[1][ky * 3] + wl[1][ky * 3 + 1] + wl[1][ky * 3 + 2]) * RS[ky]
            - wl[1][ky * 3] * E1[ky] - wl[1][ky * 3 + 2] * E0[ky];
    }
    qhm[(size_t)(b * 256 + c) * 64 + lane] = vq * (1.f / 64.f) + bl[0];
    khm[(size_t)(b * 256 + c) * 64 + lane] = vk * (1.f / 64.f) + bl[1];
  } else if (wave == 1) {
    float cs = 0.f, f0 = 0.f, f1 = 0.f;
#pragma unroll
    for (int r = 0; r < 64; r++) {
      float v = xs[(r + 1) * 68 + 4 + lane];
      cs += v;
      if (r == 0) f0 = v;
      if (r == 63) f1 = v;
    }
    float csP = __shfl(cs, lane - 1, 64); csP = (lane == 0) ? 0.f : csP;
    float csN = __shfl(cs, lane + 1, 64); csN = (lane == 63) ? 0.f : csN;
    float f0P = __shfl(f0, lane - 1, 64); f0P = (lane == 0) ? 0.f : f0P;
    float f0N = __shfl(f0, lane + 1, 64); f0N = (lane == 63) ? 0.f : f0N;
    float f1P = __shfl(f1, lane - 1, 64); f1P = (lane == 0) ? 0.f : f1P;
    float f1N = __shfl(f1, lane + 1, 64); f1N = (lane == 63) ? 0.f : f1N;
    float CS[3] = {csP, cs, csN};
    float F0[3] = {f0P, f0, f0N};
    float F1[3] = {f1P, f1, f1N};
    float vq = 0.f, vk = 0.f;
#pragma unroll
    for (int kx = 0; kx < 3; kx++) {
      vq += (wl[3][kx] + wl[3][3 + kx] + wl[3][6 + kx]) * CS[kx]
            - wl[3][kx] * F1[kx] - wl[3][6 + kx] * F0[kx];
      vk += (wl[4][kx] + wl[4][3 + kx] + wl[4][6 + kx]) * CS[kx]
            - wl[4][kx] * F1[kx] - wl[4][6 + kx] * F0[kx];
    }
    qwm[(size_t)(b * 256 + c) * 64 + lane] = vq * (1.f / 64.f) + bl[3];
    kwm[(size_t)(b * 256 + c) * 64 + lane] = vk * (1.f / 64.f) + bl[4];
  }
}

// ---------------------------------------------------------------------------
// K2v (fused launch): bx<512: vlin GEMM, 128m x 256n tile, A transposed from
// convV [b][k=256][m=4096], B=Wv bf16 [n][k] via global_load_lds.
// bx in [512,768): the pooled q/k linear GEMM, LDS aliased.
// ---------------------------------------------------------------------------
__global__ __launch_bounds__(256) void k_mmv(
    const ushort* __restrict__ A, const ushort* __restrict__ W,
    const float* __restrict__ bias, ushort* __restrict__ out,
    const float* __restrict__ s0, const float* __restrict__ s1,
    const float* __restrict__ s2, const float* __restrict__ s3,
    const ushort* __restrict__ whl,
    const float* __restrict__ b0, const float* __restrict__ b1,
    const float* __restrict__ b2, const float* __restrict__ b3,
    float* __restrict__ d0, float* __restrict__ d1,
    float* __restrict__ d2, float* __restrict__ d3) {
  __shared__ __align__(16) ushort pool[17408];   // 34816 B union

  int bx = blockIdx.x;
  int tid = threadIdx.x;
  int lane = tid & 63, wave = tid >> 6;
  int tm = lane & 15, quad = lane >> 4;

  if (bx < 512) {
    // ---------------- vlin GEMM path ----------------
    ushort* As = pool;           // 128 rows x 32 k (64B rows)
    ushort* Bs = pool + 4096;    // 256 rows x 32 k

    int m0 = bx * 128;
    int wm = (wave & 1) * 64, wn = (wave >> 1) * 128;
    int xorv = (tm ^ (tm >> 2)) & 3;
    int srow = lane >> 2;
    int slot = lane & 3;

    const ushort* Abase = A + (size_t)(m0 >> 12) * (256 * 4096) + (m0 & 4095);

    f4v acc[4][8] = {};

    for (int kc = 0; kc < 256; kc += 32) {
      __syncthreads();
      // As: LDS transpose (register path), XOR slot layout
      {
        int kr2 = (tid & 15) * 2, mg = tid >> 4;
        u8v v0 = *(const u8v*)&Abase[(size_t)(kc + kr2) * 4096 + mg * 8];
        u8v v1 = *(const u8v*)&Abase[(size_t)(kc + kr2 + 1) * 4096 + mg * 8];
        int sl0 = kr2 >> 3, k7 = kr2 & 7;
#pragma unroll
        for (int j = 0; j < 8; j++) {
          int row = mg * 8 + j;
          int xr = (row ^ (row >> 2)) & 3;
          ushort pr[2] = {v0[j], v1[j]};
          *(uint*)&As[row * 32 + (sl0 ^ xr) * 8 + k7] = *(uint*)pr;
        }
      }
      // Bs: 256 rows via direct-to-LDS DMA (4 per wave)
#pragma unroll
      for (int it = 0; it < 4; it++) {
        int rb = wave * 16 + it * 64;
        int row = rb + srow;
        int xr = (row ^ (row >> 2)) & 3;
        gload16(&W[(size_t)row * 256 + kc + (slot ^ xr) * 8], &Bs[rb * 32]);
      }
      __syncthreads();

      s8v a[4];
#pragma unroll
      for (int mi = 0; mi < 4; mi++)
        a[mi] = *(const s8v*)&As[(wm + mi * 16 + tm) * 32 + (quad ^ xorv) * 8];
#pragma unroll
      for (int ni = 0; ni < 8; ni++) {
        s8v bfr =
            *(const s8v*)&Bs[(wn + ni * 16 + tm) * 32 + (quad ^ xorv) * 8];
#pragma unroll
        for (int mi = 0; mi < 4; mi++)
          acc[mi][ni] = __builtin_amdgcn_mfma_f32_16x16x32_bf16(
              a[mi], bfr, acc[mi][ni], 0, 0, 0);
      }
    }

    // C/D layout: col = lane&15, row = quad*4 + reg
#pragma unroll
    for (int mi = 0; mi < 4; mi++) {
#pragma unroll
      for (int ni = 0; ni < 8; ni++) {
        int col = wn + ni * 16 + tm;
        float bv = bias[col];
#pragma unroll
        for (int r = 0; r < 4; r++) {
          int row = m0 + wm + mi * 16 + quad * 4 + r;
          out[(size_t)row * 256 + col] = f2bf(acc[mi][ni][r] + bv);
        }
      }
    }
    return;
  }

  // ---------------- pooled q/k linear path ----------------
  {
    int t = bx - 512;             // 0..255
    int z = t & 3;
    int n0 = ((t >> 2) & 3) * 64;
    int b = t >> 4;

    ushort* Ah = pool;            // 64*68
    ushort* Al = pool + 4352;
    ushort* Wh = pool + 8704;
    ushort* Wl = pool + 13056;

    const float* At = z == 0 ? s0 : z == 1 ? s1 : z == 2 ? s2 : s3;
    const ushort* Whp = whl + (size_t)z * 131072;
    const ushort* Wlp = Whp + 65536;
    const float* biasz = z == 0 ? b0 : z == 1 ? b1 : z == 2 ? b2 : b3;
    float* Cout = z == 0 ? d0 : z == 1 ? d1 : z == 2 ? d2 : d3;

    const float* Ab = At + (size_t)b * 256 * 64;  // [k][m], m contiguous

    int wm = (wave & 1) * 32, wn = (wave >> 1) * 32;

    f4v acc[2][2] = {};

    for (int kc = 0; kc < 256; kc += 64) {
      __syncthreads();
#pragma unroll
      for (int t2 = 0; t2 < 2; t2++) {
        int task = tid + t2 * 256;       // 0..511
        int mq = task & 15, kp = task >> 4;
        int k0 = kp * 2, m0 = mq * 4;
        float4 v0 = *(const float4*)&Ab[(size_t)(kc + k0) * 64 + m0];
        float4 v1 = *(const float4*)&Ab[(size_t)(kc + k0 + 1) * 64 + m0];
        float f0[4] = {v0.x, v0.y, v0.z, v0.w};
        float f1[4] = {v1.x, v1.y, v1.z, v1.w};
#pragma unroll
        for (int j = 0; j < 4; j++) {
          ushort h0 = f2bf(f0[j]), h1 = f2bf(f1[j]);
          ushort l0 = f2bf(f0[j] - bf2f(h0)), l1 = f2bf(f1[j] - bf2f(h1));
          ushort ph[2] = {h0, h1};
          ushort pl[2] = {l0, l1};
          *(uint*)&Ah[(m0 + j) * 68 + k0] = *(uint*)ph;
          *(uint*)&Al[(m0 + j) * 68 + k0] = *(uint*)pl;
        }
      }
#pragma unroll
      for (int t2 = 0; t2 < 2; t2++) {
        int task = tid + t2 * 256;       // 0..511
        int nr = task >> 3, k8 = (task & 7) * 8;
        *(u8v*)&Wh[nr * 68 + k8] =
            *(const u8v*)&Whp[(size_t)(n0 + nr) * 256 + kc + k8];
        *(u8v*)&Wl[nr * 68 + k8] =
            *(const u8v*)&Wlp[(size_t)(n0 + nr) * 256 + kc + k8];
      }
      __syncthreads();

#pragma unroll
      for (int ks = 0; ks < 64; ks += 32) {
        s8v ah[2], al[2], bh[2], bl[2];
#pragma unroll
        for (int mi = 0; mi < 2; mi++) {
          int idx = (wm + mi * 16 + tm) * 68 + ks + quad * 8;
          union { s8v v; unsigned long long u[2]; } th, tl;
          th.u[0] = *(const unsigned long long*)&Ah[idx];
          th.u[1] = *(const unsigned long long*)&Ah[idx + 4];
          tl.u[0] = *(const unsigned long long*)&Al[idx];
          tl.u[1] = *(const unsigned long long*)&Al[idx + 4];
          ah[mi] = th.v;
          al[mi] = tl.v;
        }
#pragma unroll
        for (int ni = 0; ni < 2; ni++) {
          int idx = (wn + ni * 16 + tm) * 68 + ks + quad * 8;
          union { s8v v; unsigned long long u[2]; } th, tl;
          th.u[0] = *(const unsigned long long*)&Wh[idx];
          th.u[1] = *(const unsigned long long*)&Wh[idx + 4];
          tl.u[0] = *(const unsigned long long*)&Wl[idx];
          tl.u[1] = *(const unsigned long long*)&Wl[idx + 4];
          bh[ni] = th.v;
          bl[ni] = tl.v;
        }
#pragma unroll
        for (int mi = 0; mi < 2; mi++)
#pragma unroll
          for (int ni = 0; ni < 2; ni++) {
            acc[mi][ni] = __builtin_amdgcn_mfma_f32_16x16x32_bf16(
                ah[mi], bh[ni], acc[mi][ni], 0, 0, 0);
            acc[mi][ni] = __builtin_amdgcn_mfma_f32_16x16x32_bf16(
                ah[mi], bl[ni], acc[mi][ni], 0, 0, 0);
            acc[mi][ni] = __builtin_amdgcn_mfma_f32_16x16x32_bf16(
                al[mi], bh[ni], acc[mi][ni], 0, 0, 0);
          }
      }
    }

#pragma unroll
    for (int mi = 0; mi < 2; mi++) {
#pragma unroll
      for (int ni = 0; ni < 2; ni++) {
        int n = n0 + wn + ni * 16 + tm;
        float bv = biasz[n];
#pragma unroll
        for (int r = 0; r < 4; r++) {
          int m = b * 64 + wm + mi * 16 + quad * 4 + r;
          Cout[(size_t)m * 256 + n] = acc[mi][ni][r] + bv;
        }
      }
    }
  }
}

// ---------------------------------------------------------------------------
// K5a (MFMA + fused softmax): r1[b][hd][h=64][c=2048]
//   = softmax(qh kh^T * s + Bh) @ vlinT[64][2048]
// Block = (b, hd, n-tile of 256). Softmax computed in-block (redundant x8,
// ~1us) -> attn hi/lo bf16 directly in LDS; ah buffer & k_attn launch gone.
// qs/ks staging aliases the Bt region (phases barrier-separated).
// ---------------------------------------------------------------------------
__global__ __launch_bounds__(256) void k_av(const float* __restrict__ q,
                                            const float* __restrict__ k,
                                            const float* __restrict__ Bb,
                                            const ushort* __restrict__ vlin,
                                            ushort* __restrict__ r1,
                                            float scale) {
  __shared__ __align__(16) ushort Ah[64 * 68];   // attn hi  [i][j]
  __shared__ __align__(16) ushort Al[64 * 68];   // attn lo  [i][j]
  __shared__ __align__(16) ushort Bt[256 * 68];  // vlin^T [c][j]; scratch q/k

  int bx = blockIdx.x;
  int nt = bx & 7, hd = (bx >> 3) & 7, b = bx >> 6;
  int n0 = nt * 256;
  int tid = threadIdx.x;
  int lane = tid & 63, wave = tid >> 6;

  // ---- softmax phase: qs/ks alias Bt ----
  {
    float* qs = (float*)Bt;            // 64*33 f32
    float* ks = qs + 64 * 33;          // 64*33 f32
#pragma unroll
    for (int it = 0; it < 8; it++) {
      int f = tid + it * 256;
      int j = f >> 5, d = f & 31;
      size_t src = (size_t)(b * 64 + j) * 256 + hd * 32 + d;
      qs[j * 33 + d] = q[src];
      ks[j * 33 + d] = k[src];
    }
    __syncthreads();
    const float* Bp = Bb + (size_t)(hd * 64) * 64;
    int j = lane;
    for (int ig = 0; ig < 16; ig++) {
      int i = ig * 4 + wave;
      float dot = 0.f;
#pragma unroll
      for (int d = 0; d < 32; d++) dot += qs[i * 33 + d] * ks[j * 33 + d];
      float logit = dot * scale + Bp[i * 64 + j];
      float mx = logit;
#pragma unroll
      for (int off = 32; off > 0; off >>= 1)
        mx = fmaxf(mx, __shfl_xor(mx, off, 64));
      float e = __expf(logit - mx);
      float sum = e;
#pragma unroll
      for (int off = 32; off > 0; off >>= 1) sum += __shfl_xor(sum, off, 64);
      float a = e / sum;
      ushort hi = f2bf(a);
      Ah[i * 68 + j] = hi;
      Al[i * 68 + j] = f2bf(a - bf2f(hi));
    }
    __syncthreads();   // done reading qs/ks before Bt overwrite
  }

  // ---- stage vlin^T -> Bt[c][j], paired-j b32 transpose writes ----
  {
#pragma unroll
    for (int p = 0; p < 4; p++) {
      int task = tid + p * 256;   // 0..1023
      int jp = task & 31;         // j-pair index
      int cc = task >> 5;         // c-chunk 0..31 (8 dv each)
      int j = jp * 2;
      int c = cc * 8;             // local col base
      int gcol = n0 + c;
      int w = gcol >> 5, dv = gcol & 31;
      const ushort* vp =
          &vlin[(size_t)(b * 4096 + j * 64 + w) * 256 + hd * 32 + dv];
      u8v v0 = *(const u8v*)vp;
      u8v v1 = *(const u8v*)(vp + 64 * 256);  // next j
#pragma unroll
      for (int qq = 0; qq < 8; qq++) {
        ushort pr[2] = {(ushort)v0[qq], (ushort)v1[qq]};
        *(uint*)&Bt[(c + qq) * 68 + j] = *(uint*)pr;
      }
    }
  }
  __syncthreads();

  int tm = lane & 15, quad = lane >> 4;
  int wn = wave * 64;
  f4v acc[4][4] = {};
#pragma unroll
  for (int kc = 0; kc < 64; kc += 32) {
    s8v ah_[4], al_[4], bb[4];
#pragma unroll
    for (int mi = 0; mi < 4; mi++) {
      int idx = (mi * 16 + tm) * 68 + kc + quad * 8;
      union { s8v v; unsigned long long u[2]; } th, tl;
      th.u[0] = *(const unsigned long long*)&Ah[idx];
      th.u[1] = *(const unsigned long long*)&Ah[idx + 4];
      tl.u[0] = *(const unsigned long long*)&Al[idx];
      tl.u[1] = *(const unsigned long long*)&Al[idx + 4];
      ah_[mi] = th.v;
      al_[mi] = tl.v;
    }
#pragma unroll
    for (int ni = 0; ni < 4; ni++) {
      int idx = (wn + ni * 16 + tm) * 68 + kc + quad * 8;
      union { s8v v; unsigned long long u[2]; } tb;
      tb.u[0] = *(const unsigned long long*)&Bt[idx];
      tb.u[1] = *(const unsigned long long*)&Bt[idx + 4];
      bb[ni] = tb.v;
    }
#pragma unroll
    for (int mi = 0; mi < 4; mi++)
#pragma unroll
      for (int ni = 0; ni < 4; ni++) {
        acc[mi][ni] = __builtin_amdgcn_mfma_f32_16x16x32_bf16(
            ah_[mi], bb[ni], acc[mi][ni], 0, 0, 0);
        acc[mi][ni] = __builtin_amdgcn_mfma_f32_16x16x32_bf16(
            al_[mi], bb[ni], acc[mi][ni], 0, 0, 0);
      }
  }

  ushort* rp = r1 + (size_t)(b * 8 + hd) * 64 * 2048;
#pragma unroll
  for (int mi = 0; mi < 4; mi++) {
#pragma unroll
    for (int ni = 0; ni < 4; ni++) {
      int col = n0 + wn + ni * 16 + tm;
#pragma unroll
      for (int r = 0; r < 4; r++) {
        int row = mi * 16 + quad * 4 + r;
        rp[(size_t)row * 2048 + col] = f2bf(acc[mi][ni][r]);
      }
    }
  }
}

// ---------------------------------------------------------------------------
// K5b (MFMA + fused softmax): yT[(b*4096+h*64+w')][hd*32+dv]
//   = sum_w r1[b,hd,h,w*32+dv] * softmax_w(qw kw^T * s + Bw)[w][w']
// Block = (b, hd, h-tile of 8). Softmax computed in-block (redundant x8),
// written transposed hi/lo into Wh/Wl. qs/ks alias the As region.
// ---------------------------------------------------------------------------
__global__ __launch_bounds__(256) void k_rw(const ushort* __restrict__ r1,
                                            const float* __restrict__ q,
                                            const float* __restrict__ k,
                                            const float* __restrict__ Bb,
                                            ushort* __restrict__ yT,
                                            float scale) {
  __shared__ __align__(16) ushort As[8 * 2180];   // 34880 B; scratch q/k
  __shared__ __align__(16) ushort Wh[64 * 68];    //  8704 B  (hi) [w'][w]
  __shared__ __align__(16) ushort Wl[64 * 68];    //  8704 B  (lo)

  int bx = blockIdx.x;
  int ht = bx & 7, hd = (bx >> 3) & 7, b = bx >> 6;
  int tid = threadIdx.x;
  int lane = tid & 63, wave = tid >> 6;

  // ---- softmax phase: qs/ks alias As ----
  {
    float* qs = (float*)As;            // 64*33 f32
    float* ks = qs + 64 * 33;
#pragma unroll
    for (int it = 0; it < 8; it++) {
      int f = tid + it * 256;
      int j = f >> 5, d = f & 31;
      size_t src = (size_t)(b * 64 + j) * 256 + hd * 32 + d;
      qs[j * 33 + d] = q[src];
      ks[j * 33 + d] = k[src];
    }
    __syncthreads();
    const float* Bp = Bb + (size_t)(hd * 64) * 64;
    int j = lane;                       // w'
    for (int ig = 0; ig < 16; ig++) {
      int i = ig * 4 + wave;            // w
      float dot = 0.f;
#pragma unroll
      for (int d = 0; d < 32; d++) dot += qs[i * 33 + d] * ks[j * 33 + d];
      float logit = dot * scale + Bp[i * 64 + j];
      float mx = logit;
#pragma unroll
      for (int off = 32; off > 0; off >>= 1)
        mx = fmaxf(mx, __shfl_xor(mx, off, 64));
      float e = __expf(logit - mx);
      float sum = e;
#pragma unroll
      for (int off = 32; off > 0; off >>= 1) sum += __shfl_xor(sum, off, 64);
      float a = e / sum;
      ushort hi = f2bf(a);
      Wh[j * 68 + i] = hi;              // transposed: [w'][w]
      Wl[j * 68 + i] = f2bf(a - bf2f(hi));
    }
    __syncthreads();   // done with qs/ks before r1 staging overwrites As
  }

  // ---- stage r1 -> As[h][dv][w] (transpose, paired-w b32 writes) ----
  {
    int h = tid >> 5;                // 0..7
    int t = tid & 31;
    const ushort* rp =
        r1 + (size_t)((b * 8 + hd) * 64 + ht * 8 + h) * 2048;
#pragma unroll
    for (int i = 0; i < 4; i++) {
      int chunk = t + 32 * i;        // 0..127
      int w = (chunk >> 2) * 2;      // even w
      int dv0 = (chunk & 3) * 8;
      u8v v0 = *(const u8v*)&rp[w * 32 + dv0];
      u8v v1 = *(const u8v*)&rp[(w + 1) * 32 + dv0];
#pragma unroll
      for (int j = 0; j < 8; j++) {
        ushort pr[2] = {(ushort)v0[j], (ushort)v1[j]};
        *(uint*)&As[h * 2180 + (dv0 + j) * 68 + w] = *(uint*)pr;
      }
    }
  }
  __syncthreads();

  int tm = lane & 15, quad = lane >> 4;
  int h0 = wave * 2;
  f4v acc[4][4] = {};
#pragma unroll
  for (int kc = 0; kc < 64; kc += 32) {
    s8v a[4], bh[4], bl[4];
#pragma unroll
    for (int mi = 0; mi < 4; mi++) {
      int h = h0 + (mi >> 1);
      int dv = (mi & 1) * 16 + tm;
      int idx = h * 2180 + dv * 68 + kc + quad * 8;
      union { s8v v; unsigned long long u[2]; } t_;
      t_.u[0] = *(const unsigned long long*)&As[idx];
      t_.u[1] = *(const unsigned long long*)&As[idx + 4];
      a[mi] = t_.v;
    }
#pragma unroll
    for (int ni = 0; ni < 4; ni++) {
      int idx = (ni * 16 + tm) * 68 + kc + quad * 8;
      union { s8v v; unsigned long long u[2]; } th, tl;
      th.u[0] = *(const unsigned long long*)&Wh[idx];
      th.u[1] = *(const unsigned long long*)&Wh[idx + 4];
      tl.u[0] = *(const unsigned long long*)&Wl[idx];
      tl.u[1] = *(const unsigned long long*)&Wl[idx + 4];
      bh[ni] = th.v;
      bl[ni] = tl.v;
    }
#pragma unroll
    for (int mi = 0; mi < 4; mi++)
#pragma unroll
      for (int ni = 0; ni < 4; ni++) {
        acc[mi][ni] = __builtin_amdgcn_mfma_f32_16x16x32_bf16(
            a[mi], bh[ni], acc[mi][ni], 0, 0, 0);
        acc[mi][ni] = __builtin_amdgcn_mfma_f32_16x16x32_bf16(
            a[mi], bl[ni], acc[mi][ni], 0, 0, 0);
      }
  }

#pragma unroll
  for (int mi = 0; mi < 4; mi++) {
    int h = ht * 8 + h0 + (mi >> 1);
    int dv0 = (mi & 1) * 16 + quad * 4;
#pragma unroll
    for (int ni = 0; ni < 4; ni++) {
      int wp = ni * 16 + tm;
      ushort pk[4];
#pragma unroll
      for (int r = 0; r < 4; r++) pk[r] = f2bf(acc[mi][ni][r]);
      *(uint2*)&yT[(size_t)(b * 4096 + h * 64 + wp) * 256 + hd * 32 + dv0] =
          *(uint2*)pk;
    }
  }
}

// ---------------------------------------------------------------------------
// K_out: final GEMM, 128m x 256n (full-N: A read once), fp32 out + bias.
// A = yT [M][256] bf16 k-contig; W = fc_o bf16 [n][k]. gload16 staging.
// ---------------------------------------------------------------------------
__global__ __launch_bounds__(256) void k_out(const ushort* __restrict__ A,
                                             const ushort* __restrict__ W,
                                             const float* __restrict__ bias,
                                             float* __restrict__ out) {
  __shared__ __align__(16) ushort As[128 * 32];
  __shared__ __align__(16) ushort Bs[256 * 32];

  int m0 = blockIdx.x * 128;
  int tid = threadIdx.x;
  int lane = tid & 63, wave = tid >> 6;
  int wm = (wave & 1) * 64, wn = (wave >> 1) * 128;
  int tm = lane & 15, quad = lane >> 4;
  int xorv = (tm ^ (tm >> 2)) & 3;
  int srow = lane >> 2;
  int slot = lane & 3;

  const ushort* Abase = A + (size_t)m0 * 256;

  f4v acc[4][8] = {};

  for (int kc = 0; kc < 256; kc += 32) {
    __syncthreads();
#pragma unroll
    for (int it = 0; it < 2; it++) {
      int rb = wave * 16 + it * 64;
      int row = rb + srow;
      int xr = (row ^ (row >> 2)) & 3;
      gload16(&Abase[(size_t)row * 256 + kc + (slot ^ xr) * 8], &As[rb * 32]);
    }
#pragma unroll
    for (int it = 0; it < 4; it++) {
      int rb = wave * 16 + it * 64;
      int row = rb + srow;
      int xr = (row ^ (row >> 2)) & 3;
      gload16(&W[(size_t)row * 256 + kc + (slot ^ xr) * 8], &Bs[rb * 32]);
    }
    __syncthreads();

    s8v a[4];
#pragma unroll
    for (int mi = 0; mi < 4; mi++)
      a[mi] = *(const s8v*)&As[(wm + mi * 16 + tm) * 32 + (quad ^ xorv) * 8];
#pragma unroll
    for (int ni = 0; ni < 8; ni++) {
      s8v bfr = *(const s8v*)&Bs[(wn + ni * 16 + tm) * 32 + (quad ^ xorv) * 8];
#pragma unroll
      for (int mi = 0; mi < 4; mi++)
        acc[mi][ni] = __builtin_amdgcn_mfma_f32_16x16x32_bf16(
            a[mi], bfr, acc[mi][ni], 0, 0, 0);
    }
  }

  // C/D layout: col = lane&15, row = quad*4 + reg
#pragma unroll
  for (int mi = 0; mi < 4; mi++) {
#pragma unroll
    for (int ni = 0; ni < 8; ni++) {
      int col = wn + ni * 16 + tm;
      float bv = bias[col];
#pragma unroll
      for (int r = 0; r < 4; r++) {
        int row = m0 + wm + mi * 16 + quad * 4 + r;
        out[(size_t)row * 256 + col] = acc[mi][ni][r] + bv;
      }
    }
  }
}

// ---------------------------------------------------------------------------
extern "C" void kernel_launch(void* const* d_in, const int* in_sizes, int n_in,
                              void* d_out, int out_size, void* d_ws,
                              size_t ws_size, hipStream_t stream) {
  const float* x      = (const float*)d_in[0];
  const float* dwqh_w = (const float*)d_in[1];
  const float* dwqh_b = (const float*)d_in[2];
  const float* fcqh_w = (const float*)d_in[3];
  const float* fcqh_b = (const float*)d_in[4];
  const float* dwkh_w = (const float*)d_in[5];
  const float* dwkh_b = (const float*)d_in[6];
  const float* fckh_w = (const float*)d_in[7];
  const float* fckh_b = (const float*)d_in[8];
  const float* Bh     = (const float*)d_in[9];
  const float* dwv_w  = (const float*)d_in[10];
  const float* dwv_b  = (const float*)d_in[11];
  const float* fcv_w  = (const float*)d_in[12];
  const float* fcv_b  = (const float*)d_in[13];
  const float* dwqw_w = (const float*)d_in[14];
  const float* dwqw_b = (const float*)d_in[15];
  const float* fcqw_w = (const float*)d_in[16];
  const float* fcqw_b = (const float*)d_in[17];
  const float* dwkw_w = (const float*)d_in[18];
  const float* dwkw_b = (const float*)d_in[19];
  const float* fckw_w = (const float*)d_in[20];
  const float* fckw_b = (const float*)d_in[21];
  const float* Bw     = (const float*)d_in[22];
  const float* fco_w  = (const float*)d_in[23];
  const float* fco_b  = (const float*)d_in[24];

  char* base = (char*)d_ws;
  ushort* P1 = (ushort*)(base);                  // convV, later r1
  ushort* P2 = (ushort*)(base + 33554432);       // yT
  ushort* P3 = (ushort*)(base + 67108864);       // vlin
  ushort* whl  = (ushort*)(base + 100663296);    // 4 x (hi|lo) 65536 bf16
  ushort* wv_bf = (ushort*)(base + 101711872);   // 2 x 65536 bf16
  float* qhm = (float*)(base + 101974016);
  float* khm = qhm + 262144;
  float* qwm = khm + 262144;
  float* kwm = qwm + 262144;
  float* qhl = kwm + 262144;
  float* khl = qhl + 262144;
  float* qwl = khl + 262144;
  float* kwl = qwl + 262144;
  if (ws_size < 115000000ull) return;

  const float scale = 0.17677669529663687f;  // 32^-0.5

  k_conv<<<5632, 256, 0, stream>>>(x, dwqh_w, dwqh_b, dwkh_w, dwkh_b, dwv_w,
                                   dwv_b, dwqw_w, dwqw_b, dwkw_w, dwkw_b,
                                   fcqh_w, fckh_w, fcqw_w, fckw_w, fcv_w,
                                   fco_w, whl, wv_bf, P1,
                                   qhm, khm, qwm, kwm);
  k_mmv<<<768, 256, 0, stream>>>(P1, wv_bf, fcv_b, P3,
                                 qhm, khm, qwm, kwm, whl, fcqh_b, fckh_b,
                                 fcqw_b, fckw_b, qhl, khl, qwl, kwl);
  k_av<<<1024, 256, 0, stream>>>(qhl, khl, Bh, P3, P1, scale);
  k_rw<<<1024, 256, 0, stream>>>(P1, qwl, kwl, Bw, P2, scale);
  k_out<<<512, 256, 0, stream>>>(P2, wv_bf + 65536, fco_b, (float*)d_out);
}

// Round 8
// 277.026 us; speedup vs baseline: 1.0897x; 1.0897x over previous
//
#include <hip/hip_runtime.h>
#include <hip/hip_bf16.h>

typedef float f4v __attribute__((ext_vector_type(4)));
typedef short s8v __attribute__((ext_vector_type(8)));
typedef unsigned short u8v __attribute__((ext_vector_type(8)));

__device__ __forceinline__ float bf2f(ushort u) {
  union { unsigned int i; float f; } c; c.i = ((unsigned int)u) << 16;
  return c.f;
}
__device__ __forceinline__ ushort f2bf(float f) {
  union { ushort s; __hip_bfloat16 h; } c; c.h = __float2bfloat16(f);
  return c.s;
}
// Direct global->LDS 16B DMA. lds base must be wave-uniform; lane l writes
// lds + l*16. Source address is per-lane.
__device__ __forceinline__ void gload16(const ushort* g, ushort* l) {
  __builtin_amdgcn_global_load_lds(
      (const __attribute__((address_space(1))) unsigned int*)g,
      (__attribute__((address_space(3))) unsigned int*)l, 16, 0, 0);
}

// ---------------------------------------------------------------------------
// K1 (+prep fold): bx<4096: per (b,c) conv plane work.
// bx in [4096,5120): cast four fp32 q/k weights [o][k] to bf16 hi/lo pairs.
// bx in [5120,5632): cast fc_v|fc_o to bf16 [n][k].
// ---------------------------------------------------------------------------
__global__ __launch_bounds__(256) void k_conv(
    const float* __restrict__ x,
    const float* __restrict__ wqh, const float* __restrict__ bqh,
    const float* __restrict__ wkh, const float* __restrict__ bkh,
    const float* __restrict__ wv,  const float* __restrict__ bv,
    const float* __restrict__ wqw, const float* __restrict__ bqw,
    const float* __restrict__ wkw, const float* __restrict__ bkw,
    const float* __restrict__ fq0, const float* __restrict__ fq1,
    const float* __restrict__ fq2, const float* __restrict__ fq3,
    const float* __restrict__ fwv, const float* __restrict__ fwo,
    ushort* __restrict__ whl, ushort* __restrict__ wbf,
    ushort* __restrict__ convV,
    float* __restrict__ qhm, float* __restrict__ khm,
    float* __restrict__ qwm, float* __restrict__ kwm) {
  __shared__ float xs[68 * 68];
  __shared__ float wl[5][9];
  __shared__ float bl[5];

  int bx = blockIdx.x;
  int tid = threadIdx.x;

  if (bx >= 4096) {
    int pb = bx - 4096;
    if (pb < 1024) {
      int mat = pb >> 8;
      int i = (pb & 255) * 256 + tid;
      const float* p = mat == 0 ? fq0 : mat == 1 ? fq1 : mat == 2 ? fq2 : fq3;
      float f = p[i];
      ushort hi = f2bf(f);
      ushort lo = f2bf(f - bf2f(hi));
      whl[(size_t)mat * 131072 + i] = hi;
      whl[(size_t)mat * 131072 + 65536 + i] = lo;
    } else {
      int idx = (pb - 1024) * 256 + tid;  // 0..131071
      const float* src = (idx >> 16) ? fwo : fwv;
      wbf[idx] = f2bf(src[idx & 65535]);
    }
    return;
  }

  int b = bx >> 8;
  int c = bx & 255;
  int lane = tid & 63, wave = tid >> 6;

  const float* xp = x + (size_t)(b * 256 + c) * 4096;
#pragma unroll
  for (int i = 0; i < 4; i++) {
    int flat = tid + i * 256;          // 0..1023
    int r = flat >> 4, c4 = (flat & 15) * 4;
    float4 v = *(const float4*)(xp + r * 64 + c4);
    *(float4*)&xs[(r + 1) * 68 + 4 + c4] = v;
  }
  if (tid < 72) { xs[tid] = 0.f; xs[65 * 68 + tid] = 0.f; }
  if (tid >= 72 && tid < 200) {
    int t = tid - 72;
    int pr = (t & 63) + 1, side = t >> 6;
    xs[pr * 68 + (side ? 68 : 3)] = 0.f;
  }
  if (tid >= 200 && tid < 245) {
    int t = tid - 200;
    int cw = t / 9, wi = t % 9;
    const float* wp = cw == 0 ? wqh : cw == 1 ? wkh : cw == 2 ? wv
                    : cw == 3 ? wqw : wkw;
    wl[cw][wi] = wp[c * 9 + wi];
  } else if (tid >= 245 && tid < 250) {
    int cw = tid - 245;
    const float* bp = cw == 0 ? bqh : cw == 1 ? bkh : cw == 2 ? bv
                    : cw == 3 ? bqw : bkw;
    bl[cw] = bp[c];
  }
  __syncthreads();

  // ---- v-conv: wave handles rows h0..h0+15, lane = output col ----
  {
    int w = lane;
    int h0 = wave * 16;
    float v0 = wl[2][0], v1 = wl[2][1], v2 = wl[2][2];
    float v3 = wl[2][3], v4 = wl[2][4], v5 = wl[2][5];
    float v6 = wl[2][6], v7 = wl[2][7], v8 = wl[2][8];
    float bvv = bl[2];
    float a00 = xs[h0 * 68 + 3 + w], a01 = xs[h0 * 68 + 4 + w],
          a02 = xs[h0 * 68 + 5 + w];
    float a10 = xs[(h0 + 1) * 68 + 3 + w], a11 = xs[(h0 + 1) * 68 + 4 + w],
          a12 = xs[(h0 + 1) * 68 + 5 + w];
    ushort* cp = convV + (size_t)(b * 256 + c) * 4096 + h0 * 64 + w;
#pragma unroll
    for (int i = 0; i < 16; i++) {
      int pr = h0 + i + 2;
      float a20 = xs[pr * 68 + 3 + w];
      float a21 = xs[pr * 68 + 4 + w];
      float a22 = xs[pr * 68 + 5 + w];
      float acc = bvv;
      acc += a00 * v0 + a01 * v1 + a02 * v2;
      acc += a10 * v3 + a11 * v4 + a12 * v5;
      acc += a20 * v6 + a21 * v7 + a22 * v8;
      cp[i * 64] = f2bf(acc);
      a00 = a10; a01 = a11; a02 = a12;
      a10 = a20; a11 = a21; a12 = a22;
    }
  }

  // ---- pooled means from linearity: wave0 rows, wave1 cols ----
  if (wave == 0) {
    float rs = 0.f, e0 = 0.f, e1 = 0.f;
    const float* rowp = &xs[(lane + 1) * 68 + 4];
#pragma unroll
    for (int i = 0; i < 16; i++) {
      float4 v = *(const float4*)(rowp + i * 4);
      rs += (v.x + v.y) + (v.z + v.w);
      if (i == 0) e0 = v.x;
      if (i == 15) e1 = v.w;
    }
    float rsP = __shfl(rs, lane - 1, 64); rsP = (lane == 0) ? 0.f : rsP;
    float rsN = __shfl(rs, lane + 1, 64); rsN = (lane == 63) ? 0.f : rsN;
    float e0P = __shfl(e0, lane - 1, 64); e0P = (lane == 0) ? 0.f : e0P;
    float e0N = __shfl(e0, lane + 1, 64); e0N = (lane == 63) ? 0.f : e0N;
    float e1P = __shfl(e1, lane - 1, 64); e1P = (lane == 0) ? 0.f : e1P;
    float e1N = __shfl(e1, lane + 1, 64); e1N = (lane == 63) ? 0.f : e1N;
    float RS[3] = {rsP, rs, rsN};
    float E0[3] = {e0P, e0, e0N};
    float E1[3] = {e1P, e1, e1N};
    float vq = 0.f, vk = 0.f;
#pragma unroll
    for (int ky = 0; ky < 3; ky++) {
      vq += (wl[0][ky * 3] + wl[0][ky * 3 + 1] + wl[0][ky * 3 + 2]) * RS[ky]
            - wl[0][ky * 3] * E1[ky] - wl[0][ky * 3 + 2] * E0[ky];
      vk += (wl[1][ky * 3] + wl[1][ky * 3 + 1] + wl[1][ky * 3 + 2]) * RS[ky]
            - wl[1][ky * 3] * E1[ky] - wl[1][ky * 3 + 2] * E0[ky];
    }
    qhm[(size_t)(b * 256 + c) * 64 + lane] = vq * (1.f / 64.f) + bl[0];
    khm[(size_t)(b * 256 + c) * 64 + lane] = vk * (1.f / 64.f) + bl[1];
  } else if (wave == 1) {
    float cs = 0.f, f0 = 0.f, f1 = 0.f;
#pragma unroll
    for (int r = 0; r < 64; r++) {
      float v = xs[(r + 1) * 68 + 4 + lane];
      cs += v;
      if (r == 0) f0 = v;
      if (r == 63) f1 = v;
    }
    float csP = __shfl(cs, lane - 1, 64); csP = (lane == 0) ? 0.f : csP;
    float csN = __shfl(cs, lane + 1, 64); csN = (lane == 63) ? 0.f : csN;
    float f0P = __shfl(f0, lane - 1, 64); f0P = (lane == 0) ? 0.f : f0P;
    float f0N = __shfl(f0, lane + 1, 64); f0N = (lane == 63) ? 0.f : f0N;
    float f1P = __shfl(f1, lane - 1, 64); f1P = (lane == 0) ? 0.f : f1P;
    float f1N = __shfl(f1, lane + 1, 64); f1N = (lane == 63) ? 0.f : f1N;
    float CS[3] = {csP, cs, csN};
    float F0[3] = {f0P, f0, f0N};
    float F1[3] = {f1P, f1, f1N};
    float vq = 0.f, vk = 0.f;
#pragma unroll
    for (int kx = 0; kx < 3; kx++) {
      vq += (wl[3][kx] + wl[3][3 + kx] + wl[3][6 + kx]) * CS[kx]
            - wl[3][kx] * F1[kx] - wl[3][6 + kx] * F0[kx];
      vk += (wl[4][kx] + wl[4][3 + kx] + wl[4][6 + kx]) * CS[kx]
            - wl[4][kx] * F1[kx] - wl[4][6 + kx] * F0[kx];
    }
    qwm[(size_t)(b * 256 + c) * 64 + lane] = vq * (1.f / 64.f) + bl[3];
    kwm[(size_t)(b * 256 + c) * 64 + lane] = vk * (1.f / 64.f) + bl[4];
  }
}

// ---------------------------------------------------------------------------
// K2v (fused launch): bx<512: vlin GEMM, 128m x 256n tile, A transposed from
// convV [b][k=256][m=4096], B=Wv bf16 [n][k] via global_load_lds.
// bx in [512,768): the pooled q/k linear GEMM, LDS aliased.
// ---------------------------------------------------------------------------
__global__ __launch_bounds__(256) void k_mmv(
    const ushort* __restrict__ A, const ushort* __restrict__ W,
    const float* __restrict__ bias, ushort* __restrict__ out,
    const float* __restrict__ s0, const float* __restrict__ s1,
    const float* __restrict__ s2, const float* __restrict__ s3,
    const ushort* __restrict__ whl,
    const float* __restrict__ b0, const float* __restrict__ b1,
    const float* __restrict__ b2, const float* __restrict__ b3,
    float* __restrict__ d0, float* __restrict__ d1,
    float* __restrict__ d2, float* __restrict__ d3) {
  __shared__ __align__(16) ushort pool[17408];   // 34816 B union

  int bx = blockIdx.x;
  int tid = threadIdx.x;
  int lane = tid & 63, wave = tid >> 6;
  int tm = lane & 15, quad = lane >> 4;

  if (bx < 512) {
    // ---------------- vlin GEMM path ----------------
    ushort* As = pool;           // 128 rows x 32 k (64B rows)
    ushort* Bs = pool + 4096;    // 256 rows x 32 k

    int m0 = bx * 128;
    int wm = (wave & 1) * 64, wn = (wave >> 1) * 128;
    int xorv = (tm ^ (tm >> 2)) & 3;
    int srow = lane >> 2;
    int slot = lane & 3;

    const ushort* Abase = A + (size_t)(m0 >> 12) * (256 * 4096) + (m0 & 4095);

    f4v acc[4][8] = {};

    for (int kc = 0; kc < 256; kc += 32) {
      __syncthreads();
      // As: LDS transpose (register path), XOR slot layout
      {
        int kr2 = (tid & 15) * 2, mg = tid >> 4;
        u8v v0 = *(const u8v*)&Abase[(size_t)(kc + kr2) * 4096 + mg * 8];
        u8v v1 = *(const u8v*)&Abase[(size_t)(kc + kr2 + 1) * 4096 + mg * 8];
        int sl0 = kr2 >> 3, k7 = kr2 & 7;
#pragma unroll
        for (int j = 0; j < 8; j++) {
          int row = mg * 8 + j;
          int xr = (row ^ (row >> 2)) & 3;
          ushort pr[2] = {v0[j], v1[j]};
          *(uint*)&As[row * 32 + (sl0 ^ xr) * 8 + k7] = *(uint*)pr;
        }
      }
      // Bs: 256 rows via direct-to-LDS DMA (4 per wave)
#pragma unroll
      for (int it = 0; it < 4; it++) {
        int rb = wave * 16 + it * 64;
        int row = rb + srow;
        int xr = (row ^ (row >> 2)) & 3;
        gload16(&W[(size_t)row * 256 + kc + (slot ^ xr) * 8], &Bs[rb * 32]);
      }
      __syncthreads();

      s8v a[4];
#pragma unroll
      for (int mi = 0; mi < 4; mi++)
        a[mi] = *(const s8v*)&As[(wm + mi * 16 + tm) * 32 + (quad ^ xorv) * 8];
#pragma unroll
      for (int ni = 0; ni < 8; ni++) {
        s8v bfr =
            *(const s8v*)&Bs[(wn + ni * 16 + tm) * 32 + (quad ^ xorv) * 8];
#pragma unroll
        for (int mi = 0; mi < 4; mi++)
          acc[mi][ni] = __builtin_amdgcn_mfma_f32_16x16x32_bf16(
              a[mi], bfr, acc[mi][ni], 0, 0, 0);
      }
    }

    // C/D layout: col = lane&15, row = quad*4 + reg
#pragma unroll
    for (int mi = 0; mi < 4; mi++) {
#pragma unroll
      for (int ni = 0; ni < 8; ni++) {
        int col = wn + ni * 16 + tm;
        float bv = bias[col];
#pragma unroll
        for (int r = 0; r < 4; r++) {
          int row = m0 + wm + mi * 16 + quad * 4 + r;
          out[(size_t)row * 256 + col] = f2bf(acc[mi][ni][r] + bv);
        }
      }
    }
    return;
  }

  // ---------------- pooled q/k linear path ----------------
  {
    int t = bx - 512;             // 0..255
    int z = t & 3;
    int n0 = ((t >> 2) & 3) * 64;
    int b = t >> 4;

    ushort* Ah = pool;            // 64*68
    ushort* Al = pool + 4352;
    ushort* Wh = pool + 8704;
    ushort* Wl = pool + 13056;

    const float* At = z == 0 ? s0 : z == 1 ? s1 : z == 2 ? s2 : s3;
    const ushort* Whp = whl + (size_t)z * 131072;
    const ushort* Wlp = Whp + 65536;
    const float* biasz = z == 0 ? b0 : z == 1 ? b1 : z == 2 ? b2 : b3;
    float* Cout = z == 0 ? d0 : z == 1 ? d1 : z == 2 ? d2 : d3;

    const float* Ab = At + (size_t)b * 256 * 64;  // [k][m], m contiguous

    int wm = (wave & 1) * 32, wn = (wave >> 1) * 32;

    f4v acc[2][2] = {};

    for (int kc = 0; kc < 256; kc += 64) {
      __syncthreads();
#pragma unroll
      for (int t2 = 0; t2 < 2; t2++) {
        int task = tid + t2 * 256;       // 0..511
        int mq = task & 15, kp = task >> 4;
        int k0 = kp * 2, m0 = mq * 4;
        float4 v0 = *(const float4*)&Ab[(size_t)(kc + k0) * 64 + m0];
        float4 v1 = *(const float4*)&Ab[(size_t)(kc + k0 + 1) * 64 + m0];
        float f0[4] = {v0.x, v0.y, v0.z, v0.w};
        float f1[4] = {v1.x, v1.y, v1.z, v1.w};
#pragma unroll
        for (int j = 0; j < 4; j++) {
          ushort h0 = f2bf(f0[j]), h1 = f2bf(f1[j]);
          ushort l0 = f2bf(f0[j] - bf2f(h0)), l1 = f2bf(f1[j] - bf2f(h1));
          ushort ph[2] = {h0, h1};
          ushort pl[2] = {l0, l1};
          *(uint*)&Ah[(m0 + j) * 68 + k0] = *(uint*)ph;
          *(uint*)&Al[(m0 + j) * 68 + k0] = *(uint*)pl;
        }
      }
#pragma unroll
      for (int t2 = 0; t2 < 2; t2++) {
        int task = tid + t2 * 256;       // 0..511
        int nr = task >> 3, k8 = (task & 7) * 8;
        *(u8v*)&Wh[nr * 68 + k8] =
            *(const u8v*)&Whp[(size_t)(n0 + nr) * 256 + kc + k8];
        *(u8v*)&Wl[nr * 68 + k8] =
            *(const u8v*)&Wlp[(size_t)(n0 + nr) * 256 + kc + k8];
      }
      __syncthreads();

#pragma unroll
      for (int ks = 0; ks < 64; ks += 32) {
        s8v ah[2], al[2], bh[2], bl[2];
#pragma unroll
        for (int mi = 0; mi < 2; mi++) {
          int idx = (wm + mi * 16 + tm) * 68 + ks + quad * 8;
          union { s8v v; unsigned long long u[2]; } th, tl;
          th.u[0] = *(const unsigned long long*)&Ah[idx];
          th.u[1] = *(const unsigned long long*)&Ah[idx + 4];
          tl.u[0] = *(const unsigned long long*)&Al[idx];
          tl.u[1] = *(const unsigned long long*)&Al[idx + 4];
          ah[mi] = th.v;
          al[mi] = tl.v;
        }
#pragma unroll
        for (int ni = 0; ni < 2; ni++) {
          int idx = (wn + ni * 16 + tm) * 68 + ks + quad * 8;
          union { s8v v; unsigned long long u[2]; } th, tl;
          th.u[0] = *(const unsigned long long*)&Wh[idx];
          th.u[1] = *(const unsigned long long*)&Wh[idx + 4];
          tl.u[0] = *(const unsigned long long*)&Wl[idx];
          tl.u[1] = *(const unsigned long long*)&Wl[idx + 4];
          bh[ni] = th.v;
          bl[ni] = tl.v;
        }
#pragma unroll
        for (int mi = 0; mi < 2; mi++)
#pragma unroll
          for (int ni = 0; ni < 2; ni++) {
            acc[mi][ni] = __builtin_amdgcn_mfma_f32_16x16x32_bf16(
                ah[mi], bh[ni], acc[mi][ni], 0, 0, 0);
            acc[mi][ni] = __builtin_amdgcn_mfma_f32_16x16x32_bf16(
                ah[mi], bl[ni], acc[mi][ni], 0, 0, 0);
            acc[mi][ni] = __builtin_amdgcn_mfma_f32_16x16x32_bf16(
                al[mi], bh[ni], acc[mi][ni], 0, 0, 0);
          }
      }
    }

#pragma unroll
    for (int mi = 0; mi < 2; mi++) {
#pragma unroll
      for (int ni = 0; ni < 2; ni++) {
        int n = n0 + wn + ni * 16 + tm;
        float bv = biasz[n];
#pragma unroll
        for (int r = 0; r < 4; r++) {
          int m = b * 64 + wm + mi * 16 + quad * 4 + r;
          Cout[(size_t)m * 256 + n] = acc[mi][ni][r] + bv;
        }
      }
    }
  }
}

// ---------------------------------------------------------------------------
// K3: attention softmax, both axes fused. Block = (set,b,hd): stages q/k
// once, loops all 16 row-quads. High occupancy, attn is L2/L3-resident for
// the consumers (fusing this into k_av/k_rw measured WORSE: low-occupancy
// serial recompute x8 > cheap cache re-reads).
// ---------------------------------------------------------------------------
__global__ __launch_bounds__(256) void k_attn(
    const float* __restrict__ qh, const float* __restrict__ kh,
    const float* __restrict__ Bh, float* __restrict__ ah,
    const float* __restrict__ qw, const float* __restrict__ kw,
    const float* __restrict__ Bw, float* __restrict__ aw, float scale) {
  __shared__ float qs[64 * 33];
  __shared__ float ks[64 * 33];

  int bx = blockIdx.x;             // 256 blocks
  int setw = bx >> 7;
  int rem = bx & 127;
  int hd = rem & 7, b = rem >> 3;
  int tid = threadIdx.x;
  int wave = tid >> 6, lane = tid & 63;

  const float* q = setw ? qw : qh;
  const float* k = setw ? kw : kh;
  const float* Bb = setw ? Bw : Bh;
  float* attn = setw ? aw : ah;

#pragma unroll
  for (int it = 0; it < 8; it++) {
    int f = tid + it * 256;
    int j = f >> 5, d = f & 31;
    size_t src = (size_t)(b * 64 + j) * 256 + hd * 32 + d;
    qs[j * 33 + d] = q[src];
    ks[j * 33 + d] = k[src];
  }
  __syncthreads();

  const float* Bp = Bb + (size_t)(hd * 64) * 64;
  float* ap = attn + (size_t)((b * 8 + hd) * 64) * 64;
  int j = lane;
  for (int ig = 0; ig < 16; ig++) {
    int i = ig * 4 + wave;
    float dot = 0.f;
#pragma unroll
    for (int d = 0; d < 32; d++) dot += qs[i * 33 + d] * ks[j * 33 + d];
    float logit = dot * scale + Bp[i * 64 + j];
    float mx = logit;
#pragma unroll
    for (int off = 32; off > 0; off >>= 1)
      mx = fmaxf(mx, __shfl_xor(mx, off, 64));
    float e = __expf(logit - mx);
    float sum = e;
#pragma unroll
    for (int off = 32; off > 0; off >>= 1) sum += __shfl_xor(sum, off, 64);
    ap[i * 64 + j] = e / sum;
  }
}

// ---------------------------------------------------------------------------
// K5a (MFMA): r1[b][hd][h=64][c=2048] = attn_h[64x64] @ vlinT[64][2048]
// ---------------------------------------------------------------------------
__global__ __launch_bounds__(256) void k_av(const float* __restrict__ attn,
                                            const ushort* __restrict__ vlin,
                                            ushort* __restrict__ r1) {
  __shared__ __align__(16) ushort Ah[64 * 68];   // attn hi  [i][j]
  __shared__ __align__(16) ushort Al[64 * 68];   // attn lo  [i][j]
  __shared__ __align__(16) ushort Bt[256 * 68];  // vlin^T   [c][j]

  int bx = blockIdx.x;
  int nt = bx & 7, hd = (bx >> 3) & 7, b = bx >> 6;
  int n0 = nt * 256;
  int tid = threadIdx.x;
  int lane = tid & 63, wave = tid >> 6;

  const float* ap = attn + (size_t)(b * 8 + hd) * 4096;
  {
    int i = tid >> 2;          // row 0..63
    int j0 = (tid & 3) * 16;   // 16 cols per thread
#pragma unroll
    for (int p = 0; p < 4; p++) {
      float4 v = *(const float4*)&ap[i * 64 + j0 + p * 4];
      float f_[4] = {v.x, v.y, v.z, v.w};
      ushort ph[4], pl[4];
#pragma unroll
      for (int q = 0; q < 4; q++) {
        ph[q] = f2bf(f_[q]);
        pl[q] = f2bf(f_[q] - bf2f(ph[q]));
      }
      *(uint2*)&Ah[i * 68 + j0 + p * 4] = *(uint2*)ph;
      *(uint2*)&Al[i * 68 + j0 + p * 4] = *(uint2*)pl;
    }
  }
  {
#pragma unroll
    for (int p = 0; p < 4; p++) {
      int task = tid + p * 256;   // 0..1023
      int jp = task & 31;         // j-pair index
      int cc = task >> 5;         // c-chunk 0..31 (8 dv each)
      int j = jp * 2;
      int c = cc * 8;             // local col base
      int gcol = n0 + c;
      int w = gcol >> 5, dv = gcol & 31;
      const ushort* vp =
          &vlin[(size_t)(b * 4096 + j * 64 + w) * 256 + hd * 32 + dv];
      u8v v0 = *(const u8v*)vp;
      u8v v1 = *(const u8v*)(vp + 64 * 256);  // next j
#pragma unroll
      for (int q = 0; q < 8; q++) {
        ushort pr[2] = {(ushort)v0[q], (ushort)v1[q]};
        *(uint*)&Bt[(c + q) * 68 + j] = *(uint*)pr;
      }
    }
  }
  __syncthreads();

  int tm = lane & 15, quad = lane >> 4;
  int wn = wave * 64;
  f4v acc[4][4] = {};
#pragma unroll
  for (int kc = 0; kc < 64; kc += 32) {
    s8v ah_[4], al_[4], bb[4];
#pragma unroll
    for (int mi = 0; mi < 4; mi++) {
      int idx = (mi * 16 + tm) * 68 + kc + quad * 8;
      union { s8v v; unsigned long long u[2]; } th, tl;
      th.u[0] = *(const unsigned long long*)&Ah[idx];
      th.u[1] = *(const unsigned long long*)&Ah[idx + 4];
      tl.u[0] = *(const unsigned long long*)&Al[idx];
      tl.u[1] = *(const unsigned long long*)&Al[idx + 4];
      ah_[mi] = th.v;
      al_[mi] = tl.v;
    }
#pragma unroll
    for (int ni = 0; ni < 4; ni++) {
      int idx = (wn + ni * 16 + tm) * 68 + kc + quad * 8;
      union { s8v v; unsigned long long u[2]; } tb;
      tb.u[0] = *(const unsigned long long*)&Bt[idx];
      tb.u[1] = *(const unsigned long long*)&Bt[idx + 4];
      bb[ni] = tb.v;
    }
#pragma unroll
    for (int mi = 0; mi < 4; mi++)
#pragma unroll
      for (int ni = 0; ni < 4; ni++) {
        acc[mi][ni] = __builtin_amdgcn_mfma_f32_16x16x32_bf16(
            ah_[mi], bb[ni], acc[mi][ni], 0, 0, 0);
        acc[mi][ni] = __builtin_amdgcn_mfma_f32_16x16x32_bf16(
            al_[mi], bb[ni], acc[mi][ni], 0, 0, 0);
      }
  }

  ushort* rp = r1 + (size_t)(b * 8 + hd) * 64 * 2048;
#pragma unroll
  for (int mi = 0; mi < 4; mi++) {
#pragma unroll
    for (int ni = 0; ni < 4; ni++) {
      int col = n0 + wn + ni * 16 + tm;
#pragma unroll
      for (int r = 0; r < 4; r++) {
        int row = mi * 16 + quad * 4 + r;
        rp[(size_t)row * 2048 + col] = f2bf(acc[mi][ni][r]);
      }
    }
  }
}

// ---------------------------------------------------------------------------
// K5b (MFMA): yT[(b*4096+h*64+w')][hd*32+dv]
//               = sum_w r1[b,hd,h,w*32+dv] * attnw[w][w']
// ---------------------------------------------------------------------------
__global__ __launch_bounds__(256) void k_rw(const ushort* __restrict__ r1,
                                            const float* __restrict__ attnw,
                                            ushort* __restrict__ yT) {
  __shared__ __align__(16) ushort As[8 * 2180];   // 34880 B
  __shared__ __align__(16) ushort Wh[64 * 68];    //  8704 B  (hi)
  __shared__ __align__(16) ushort Wl[64 * 68];    //  8704 B  (lo)

  int bx = blockIdx.x;
  int ht = bx & 7, hd = (bx >> 3) & 7, b = bx >> 6;
  int tid = threadIdx.x;
  int lane = tid & 63, wave = tid >> 6;

  {
    int h = tid >> 5;                // 0..7
    int t = tid & 31;
    const ushort* rp =
        r1 + (size_t)((b * 8 + hd) * 64 + ht * 8 + h) * 2048;
#pragma unroll
    for (int i = 0; i < 4; i++) {
      int chunk = t + 32 * i;        // 0..127
      int w = (chunk >> 2) * 2;      // even w
      int dv0 = (chunk & 3) * 8;
      u8v v0 = *(const u8v*)&rp[w * 32 + dv0];
      u8v v1 = *(const u8v*)&rp[(w + 1) * 32 + dv0];
#pragma unroll
      for (int j = 0; j < 8; j++) {
        ushort pr[2] = {(ushort)v0[j], (ushort)v1[j]};
        *(uint*)&As[h * 2180 + (dv0 + j) * 68 + w] = *(uint*)pr;
      }
    }
  }
  {
    const float* ap = attnw + (size_t)(b * 8 + hd) * 4096;
#pragma unroll
    for (int p = 0; p < 4; p++) {
      int w = (tid >> 4) + p * 16;
      int wq = (tid & 15) * 4;
      float4 v = *(const float4*)&ap[w * 64 + wq];
      float f_[4] = {v.x, v.y, v.z, v.w};
#pragma unroll
      for (int j = 0; j < 4; j++) {
        ushort hi = f2bf(f_[j]);
        Wh[(wq + j) * 68 + w] = hi;
        Wl[(wq + j) * 68 + w] = f2bf(f_[j] - bf2f(hi));
      }
    }
  }
  __syncthreads();

  int tm = lane & 15, quad = lane >> 4;
  int h0 = wave * 2;
  f4v acc[4][4] = {};
#pragma unroll
  for (int kc = 0; kc < 64; kc += 32) {
    s8v a[4], bh[4], bl[4];
#pragma unroll
    for (int mi = 0; mi < 4; mi++) {
      int h = h0 + (mi >> 1);
      int dv = (mi & 1) * 16 + tm;
      int idx = h * 2180 + dv * 68 + kc + quad * 8;
      union { s8v v; unsigned long long u[2]; } t_;
      t_.u[0] = *(const unsigned long long*)&As[idx];
      t_.u[1] = *(const unsigned long long*)&As[idx + 4];
      a[mi] = t_.v;
    }
#pragma unroll
    for (int ni = 0; ni < 4; ni++) {
      int idx = (ni * 16 + tm) * 68 + kc + quad * 8;
      union { s8v v; unsigned long long u[2]; } th, tl;
      th.u[0] = *(const unsigned long long*)&Wh[idx];
      th.u[1] = *(const unsigned long long*)&Wh[idx + 4];
      tl.u[0] = *(const unsigned long long*)&Wl[idx];
      tl.u[1] = *(const unsigned long long*)&Wl[idx + 4];
      bh[ni] = th.v;
      bl[ni] = tl.v;
    }
#pragma unroll
    for (int mi = 0; mi < 4; mi++)
#pragma unroll
      for (int ni = 0; ni < 4; ni++) {
        acc[mi][ni] = __builtin_amdgcn_mfma_f32_16x16x32_bf16(
            a[mi], bh[ni], acc[mi][ni], 0, 0, 0);
        acc[mi][ni] = __builtin_amdgcn_mfma_f32_16x16x32_bf16(
            a[mi], bl[ni], acc[mi][ni], 0, 0, 0);
      }
  }

#pragma unroll
  for (int mi = 0; mi < 4; mi++) {
    int h = ht * 8 + h0 + (mi >> 1);
    int dv0 = (mi & 1) * 16 + quad * 4;
#pragma unroll
    for (int ni = 0; ni < 4; ni++) {
      int wp = ni * 16 + tm;
      ushort pk[4];
#pragma unroll
      for (int r = 0; r < 4; r++) pk[r] = f2bf(acc[mi][ni][r]);
      *(uint2*)&yT[(size_t)(b * 4096 + h * 64 + wp) * 256 + hd * 32 + dv0] =
          *(uint2*)pk;
    }
  }
}

// ---------------------------------------------------------------------------
// K_out: final GEMM, 128m x 256n (full-N: A read once), fp32 out + bias.
// A = yT [M][256] bf16 k-contig; W = fc_o bf16 [n][k]. gload16 staging.
// ---------------------------------------------------------------------------
__global__ __launch_bounds__(256) void k_out(const ushort* __restrict__ A,
                                             const ushort* __restrict__ W,
                                             const float* __restrict__ bias,
                                             float* __restrict__ out) {
  __shared__ __align__(16) ushort As[128 * 32];
  __shared__ __align__(16) ushort Bs[256 * 32];

  int m0 = blockIdx.x * 128;
  int tid = threadIdx.x;
  int lane = tid & 63, wave = tid >> 6;
  int wm = (wave & 1) * 64, wn = (wave >> 1) * 128;
  int tm = lane & 15, quad = lane >> 4;
  int xorv = (tm ^ (tm >> 2)) & 3;
  int srow = lane >> 2;
  int slot = lane & 3;

  const ushort* Abase = A + (size_t)m0 * 256;

  f4v acc[4][8] = {};

  for (int kc = 0; kc < 256; kc += 32) {
    __syncthreads();
#pragma unroll
    for (int it = 0; it < 2; it++) {
      int rb = wave * 16 + it * 64;
      int row = rb + srow;
      int xr = (row ^ (row >> 2)) & 3;
      gload16(&Abase[(size_t)row * 256 + kc + (slot ^ xr) * 8], &As[rb * 32]);
    }
#pragma unroll
    for (int it = 0; it < 4; it++) {
      int rb = wave * 16 + it * 64;
      int row = rb + srow;
      int xr = (row ^ (row >> 2)) & 3;
      gload16(&W[(size_t)row * 256 + kc + (slot ^ xr) * 8], &Bs[rb * 32]);
    }
    __syncthreads();

    s8v a[4];
#pragma unroll
    for (int mi = 0; mi < 4; mi++)
      a[mi] = *(const s8v*)&As[(wm + mi * 16 + tm) * 32 + (quad ^ xorv) * 8];
#pragma unroll
    for (int ni = 0; ni < 8; ni++) {
      s8v bfr = *(const s8v*)&Bs[(wn + ni * 16 + tm) * 32 + (quad ^ xorv) * 8];
#pragma unroll
      for (int mi = 0; mi < 4; mi++)
        acc[mi][ni] = __builtin_amdgcn_mfma_f32_16x16x32_bf16(
            a[mi], bfr, acc[mi][ni], 0, 0, 0);
    }
  }

  // C/D layout: col = lane&15, row = quad*4 + reg
#pragma unroll
  for (int mi = 0; mi < 4; mi++) {
#pragma unroll
    for (int ni = 0; ni < 8; ni++) {
      int col = wn + ni * 16 + tm;
      float bv = bias[col];
#pragma unroll
      for (int r = 0; r < 4; r++) {
        int row = m0 + wm + mi * 16 + quad * 4 + r;
        out[(size_t)row * 256 + col] = acc[mi][ni][r] + bv;
      }
    }
  }
}

// ---------------------------------------------------------------------------
extern "C" void kernel_launch(void* const* d_in, const int* in_sizes, int n_in,
                              void* d_out, int out_size, void* d_ws,
                              size_t ws_size, hipStream_t stream) {
  const float* x      = (const float*)d_in[0];
  const float* dwqh_w = (const float*)d_in[1];
  const float* dwqh_b = (const float*)d_in[2];
  const float* fcqh_w = (const float*)d_in[3];
  const float* fcqh_b = (const float*)d_in[4];
  const float* dwkh_w = (const float*)d_in[5];
  const float* dwkh_b = (const float*)d_in[6];
  const float* fckh_w = (const float*)d_in[7];
  const float* fckh_b = (const float*)d_in[8];
  const float* Bh     = (const float*)d_in[9];
  const float* dwv_w  = (const float*)d_in[10];
  const float* dwv_b  = (const float*)d_in[11];
  const float* fcv_w  = (const float*)d_in[12];
  const float* fcv_b  = (const float*)d_in[13];
  const float* dwqw_w = (const float*)d_in[14];
  const float* dwqw_b = (const float*)d_in[15];
  const float* fcqw_w = (const float*)d_in[16];
  const float* fcqw_b = (const float*)d_in[17];
  const float* dwkw_w = (const float*)d_in[18];
  const float* dwkw_b = (const float*)d_in[19];
  const float* fckw_w = (const float*)d_in[20];
  const float* fckw_b = (const float*)d_in[21];
  const float* Bw     = (const float*)d_in[22];
  const float* fco_w  = (const float*)d_in[23];
  const float* fco_b  = (const float*)d_in[24];

  char* base = (char*)d_ws;
  ushort* P1 = (ushort*)(base);                  // convV, later r1
  ushort* P2 = (ushort*)(base + 33554432);       // yT
  ushort* P3 = (ushort*)(base + 67108864);       // vlin
  ushort* whl  = (ushort*)(base + 100663296);    // 4 x (hi|lo) 65536 bf16
  ushort* wv_bf = (ushort*)(base + 101711872);   // 2 x 65536 bf16
  float* qhm = (float*)(base + 101974016);
  float* khm = qhm + 262144;
  float* qwm = khm + 262144;
  float* kwm = qwm + 262144;
  float* qhl = kwm + 262144;
  float* khl = qhl + 262144;
  float* qwl = khl + 262144;
  float* kwl = qwl + 262144;
  float* ah  = kwl + 262144;                     // 524288
  float* awt = ah + 524288;                      // 524288
  if (ws_size < 115000000ull) return;

  const float scale = 0.17677669529663687f;  // 32^-0.5

  k_conv<<<5632, 256, 0, stream>>>(x, dwqh_w, dwqh_b, dwkh_w, dwkh_b, dwv_w,
                                   dwv_b, dwqw_w, dwqw_b, dwkw_w, dwkw_b,
                                   fcqh_w, fckh_w, fcqw_w, fckw_w, fcv_w,
                                   fco_w, whl, wv_bf, P1,
                                   qhm, khm, qwm, kwm);
  k_mmv<<<768, 256, 0, stream>>>(P1, wv_bf, fcv_b, P3,
                                 qhm, khm, qwm, kwm, whl, fcqh_b, fckh_b,
                                 fcqw_b, fckw_b, qhl, khl, qwl, kwl);
  k_attn<<<256, 256, 0, stream>>>(qhl, khl, Bh, ah, qwl, kwl, Bw, awt, scale);
  k_av<<<1024, 256, 0, stream>>>(ah, P3, P1);
  k_rw<<<1024, 256, 0, stream>>>(P1, awt, P2);
  k_out<<<512, 256, 0, stream>>>(P2, wv_bf + 65536, fco_b, (float*)d_out);
}

// Round 10
// 275.460 us; speedup vs baseline: 1.0959x; 1.0057x over previous
//
#include <hip/hip_runtime.h>
#include <hip/hip_bf16.h>

typedef float f4v __attribute__((ext_vector_type(4)));
typedef short s8v __attribute__((ext_vector_type(8)));
typedef unsigned short u8v __attribute__((ext_vector_type(8)));

__device__ __forceinline__ float bf2f(ushort u) {
  union { unsigned int i; float f; } c; c.i = ((unsigned int)u) << 16;
  return c.f;
}
__device__ __forceinline__ ushort f2bf(float f) {
  union { ushort s; __hip_bfloat16 h; } c; c.h = __float2bfloat16(f);
  return c.s;
}
// Direct global->LDS 16B DMA. lds base must be wave-uniform; lane l writes
// lds + l*16. Source address is per-lane.
__device__ __forceinline__ void gload16(const ushort* g, ushort* l) {
  __builtin_amdgcn_global_load_lds(
      (const __attribute__((address_space(1))) unsigned int*)g,
      (__attribute__((address_space(3))) unsigned int*)l, 16, 0, 0);
}

// ---------------------------------------------------------------------------
// K1 (+prep fold): bx<4096: per (b,c) conv plane work.
// bx in [4096,5120): cast four fp32 q/k weights [o][k] to bf16 hi/lo pairs.
// bx in [5120,5632): cast fc_v|fc_o to bf16 [n][k].
// ---------------------------------------------------------------------------
__global__ __launch_bounds__(256) void k_conv(
    const float* __restrict__ x,
    const float* __restrict__ wqh, const float* __restrict__ bqh,
    const float* __restrict__ wkh, const float* __restrict__ bkh,
    const float* __restrict__ wv,  const float* __restrict__ bv,
    const float* __restrict__ wqw, const float* __restrict__ bqw,
    const float* __restrict__ wkw, const float* __restrict__ bkw,
    const float* __restrict__ fq0, const float* __restrict__ fq1,
    const float* __restrict__ fq2, const float* __restrict__ fq3,
    const float* __restrict__ fwv, const float* __restrict__ fwo,
    ushort* __restrict__ whl, ushort* __restrict__ wbf,
    ushort* __restrict__ convV,
    float* __restrict__ qhm, float* __restrict__ khm,
    float* __restrict__ qwm, float* __restrict__ kwm) {
  __shared__ float xs[68 * 68];
  __shared__ float wl[5][9];
  __shared__ float bl[5];

  int bx = blockIdx.x;
  int tid = threadIdx.x;

  if (bx >= 4096) {
    int pb = bx - 4096;
    if (pb < 1024) {
      int mat = pb >> 8;
      int i = (pb & 255) * 256 + tid;
      const float* p = mat == 0 ? fq0 : mat == 1 ? fq1 : mat == 2 ? fq2 : fq3;
      float f = p[i];
      ushort hi = f2bf(f);
      ushort lo = f2bf(f - bf2f(hi));
      whl[(size_t)mat * 131072 + i] = hi;
      whl[(size_t)mat * 131072 + 65536 + i] = lo;
    } else {
      int idx = (pb - 1024) * 256 + tid;  // 0..131071
      const float* src = (idx >> 16) ? fwo : fwv;
      wbf[idx] = f2bf(src[idx & 65535]);
    }
    return;
  }

  int b = bx >> 8;
  int c = bx & 255;
  int lane = tid & 63, wave = tid >> 6;

  const float* xp = x + (size_t)(b * 256 + c) * 4096;
#pragma unroll
  for (int i = 0; i < 4; i++) {
    int flat = tid + i * 256;          // 0..1023
    int r = flat >> 4, c4 = (flat & 15) * 4;
    float4 v = *(const float4*)(xp + r * 64 + c4);
    *(float4*)&xs[(r + 1) * 68 + 4 + c4] = v;
  }
  if (tid < 72) { xs[tid] = 0.f; xs[65 * 68 + tid] = 0.f; }
  if (tid >= 72 && tid < 200) {
    int t = tid - 72;
    int pr = (t & 63) + 1, side = t >> 6;
    xs[pr * 68 + (side ? 68 : 3)] = 0.f;
  }
  if (tid >= 200 && tid < 245) {
    int t = tid - 200;
    int cw = t / 9, wi = t % 9;
    const float* wp = cw == 0 ? wqh : cw == 1 ? wkh : cw == 2 ? wv
                    : cw == 3 ? wqw : wkw;
    wl[cw][wi] = wp[c * 9 + wi];
  } else if (tid >= 245 && tid < 250) {
    int cw = tid - 245;
    const float* bp = cw == 0 ? bqh : cw == 1 ? bkh : cw == 2 ? bv
                    : cw == 3 ? bqw : bkw;
    bl[cw] = bp[c];
  }
  __syncthreads();

  // ---- v-conv: wave handles rows h0..h0+15, lane = output col ----
  {
    int w = lane;
    int h0 = wave * 16;
    float v0 = wl[2][0], v1 = wl[2][1], v2 = wl[2][2];
    float v3 = wl[2][3], v4 = wl[2][4], v5 = wl[2][5];
    float v6 = wl[2][6], v7 = wl[2][7], v8 = wl[2][8];
    float bvv = bl[2];
    float a00 = xs[h0 * 68 + 3 + w], a01 = xs[h0 * 68 + 4 + w],
          a02 = xs[h0 * 68 + 5 + w];
    float a10 = xs[(h0 + 1) * 68 + 3 + w], a11 = xs[(h0 + 1) * 68 + 4 + w],
          a12 = xs[(h0 + 1) * 68 + 5 + w];
    ushort* cp = convV + (size_t)(b * 256 + c) * 4096 + h0 * 64 + w;
#pragma unroll
    for (int i = 0; i < 16; i++) {
      int pr = h0 + i + 2;
      float a20 = xs[pr * 68 + 3 + w];
      float a21 = xs[pr * 68 + 4 + w];
      float a22 = xs[pr * 68 + 5 + w];
      float acc = bvv;
      acc += a00 * v0 + a01 * v1 + a02 * v2;
      acc += a10 * v3 + a11 * v4 + a12 * v5;
      acc += a20 * v6 + a21 * v7 + a22 * v8;
      cp[i * 64] = f2bf(acc);
      a00 = a10; a01 = a11; a02 = a12;
      a10 = a20; a11 = a21; a12 = a22;
    }
  }

  // ---- pooled means from linearity: wave0 rows, wave1 cols ----
  if (wave == 0) {
    float rs = 0.f, e0 = 0.f, e1 = 0.f;
    const float* rowp = &xs[(lane + 1) * 68 + 4];
#pragma unroll
    for (int i = 0; i < 16; i++) {
      float4 v = *(const float4*)(rowp + i * 4);
      rs += (v.x + v.y) + (v.z + v.w);
      if (i == 0) e0 = v.x;
      if (i == 15) e1 = v.w;
    }
    float rsP = __shfl(rs, lane - 1, 64); rsP = (lane == 0) ? 0.f : rsP;
    float rsN = __shfl(rs, lane + 1, 64); rsN = (lane == 63) ? 0.f : rsN;
    float e0P = __shfl(e0, lane - 1, 64); e0P = (lane == 0) ? 0.f : e0P;
    float e0N = __shfl(e0, lane + 1, 64); e0N = (lane == 63) ? 0.f : e0N;
    float e1P = __shfl(e1, lane - 1, 64); e1P = (lane == 0) ? 0.f : e1P;
    float e1N = __shfl(e1, lane + 1, 64); e1N = (lane == 63) ? 0.f : e1N;
    float RS[3] = {rsP, rs, rsN};
    float E0[3] = {e0P, e0, e0N};
    float E1[3] = {e1P, e1, e1N};
    float vq = 0.f, vk = 0.f;
#pragma unroll
    for (int ky = 0; ky < 3; ky++) {
      vq += (wl[0][ky * 3] + wl[0][ky * 3 + 1] + wl[0][ky * 3 + 2]) * RS[ky]
            - wl[0][ky * 3] * E1[ky] - wl[0][ky * 3 + 2] * E0[ky];
      vk += (wl[1][ky * 3] + wl[1][ky * 3 + 1] + wl[1][ky * 3 + 2]) * RS[ky]
            - wl[1][ky * 3] * E1[ky] - wl[1][ky * 3 + 2] * E0[ky];
    }
    qhm[(size_t)(b * 256 + c) * 64 + lane] = vq * (1.f / 64.f) + bl[0];
    khm[(size_t)(b * 256 + c) * 64 + lane] = vk * (1.f / 64.f) + bl[1];
  } else if (wave == 1) {
    float cs = 0.f, f0 = 0.f, f1 = 0.f;
#pragma unroll
    for (int r = 0; r < 64; r++) {
      float v = xs[(r + 1) * 68 + 4 + lane];
      cs += v;
      if (r == 0) f0 = v;
      if (r == 63) f1 = v;
    }
    float csP = __shfl(cs, lane - 1, 64); csP = (lane == 0) ? 0.f : csP;
    float csN = __shfl(cs, lane + 1, 64); csN = (lane == 63) ? 0.f : csN;
    float f0P = __shfl(f0, lane - 1, 64); f0P = (lane == 0) ? 0.f : f0P;
    float f0N = __shfl(f0, lane + 1, 64); f0N = (lane == 63) ? 0.f : f0N;
    float f1P = __shfl(f1, lane - 1, 64); f1P = (lane == 0) ? 0.f : f1P;
    float f1N = __shfl(f1, lane + 1, 64); f1N = (lane == 63) ? 0.f : f1N;
    float CS[3] = {csP, cs, csN};
    float F0[3] = {f0P, f0, f0N};
    float F1[3] = {f1P, f1, f1N};
    float vq = 0.f, vk = 0.f;
#pragma unroll
    for (int kx = 0; kx < 3; kx++) {
      vq += (wl[3][kx] + wl[3][3 + kx] + wl[3][6 + kx]) * CS[kx]
            - wl[3][kx] * F1[kx] - wl[3][6 + kx] * F0[kx];
      vk += (wl[4][kx] + wl[4][3 + kx] + wl[4][6 + kx]) * CS[kx]
            - wl[4][kx] * F1[kx] - wl[4][6 + kx] * F0[kx];
    }
    qwm[(size_t)(b * 256 + c) * 64 + lane] = vq * (1.f / 64.f) + bl[3];
    kwm[(size_t)(b * 256 + c) * 64 + lane] = vk * (1.f / 64.f) + bl[4];
  }
}

// ---------------------------------------------------------------------------
// K2v (fused launch): bx<1024: vlin GEMM, 128m x 128n tile (round-3 shape:
// acc[4][4], low VGPR), A transposed from convV [b][k=256][m=4096],
// B=Wv bf16 [n][k] via global_load_lds.
// bx in [1024,1280): pooled q/k linear GEMM, K-chunks of 32 (stride-36 LDS,
// 18.4KB pool union -> 8 blocks/CU by LDS, up from 4).
// ---------------------------------------------------------------------------
__global__ __launch_bounds__(256) void k_mmv(
    const ushort* __restrict__ A, const ushort* __restrict__ W,
    const float* __restrict__ bias, ushort* __restrict__ out,
    const float* __restrict__ s0, const float* __restrict__ s1,
    const float* __restrict__ s2, const float* __restrict__ s3,
    const ushort* __restrict__ whl,
    const float* __restrict__ b0, const float* __restrict__ b1,
    const float* __restrict__ b2, const float* __restrict__ b3,
    float* __restrict__ d0, float* __restrict__ d1,
    float* __restrict__ d2, float* __restrict__ d3) {
  __shared__ __align__(16) ushort pool[9216];   // 18432 B union

  int bx = blockIdx.x;
  int tid = threadIdx.x;
  int lane = tid & 63, wave = tid >> 6;
  int tm = lane & 15, quad = lane >> 4;

  if (bx < 1024) {
    // ---------------- vlin GEMM path (128x128) ----------------
    ushort* As = pool;           // 128 rows x 32 k (64B rows)
    ushort* Bs = pool + 4096;    // 128 rows x 32 k

    int m0 = (bx >> 1) * 128;
    int n0 = (bx & 1) * 128;
    int wm = (wave & 1) * 64, wn = (wave >> 1) * 64;
    int xorv = (tm ^ (tm >> 2)) & 3;
    int srow = lane >> 2;
    int slot = lane & 3;

    const ushort* Abase = A + (size_t)(m0 >> 12) * (256 * 4096) + (m0 & 4095);

    f4v acc[4][4] = {};

    for (int kc = 0; kc < 256; kc += 32) {
      __syncthreads();
      // As: LDS transpose (register path), XOR slot layout
      {
        int kr2 = (tid & 15) * 2, mg = tid >> 4;
        u8v v0 = *(const u8v*)&Abase[(size_t)(kc + kr2) * 4096 + mg * 8];
        u8v v1 = *(const u8v*)&Abase[(size_t)(kc + kr2 + 1) * 4096 + mg * 8];
        int sl0 = kr2 >> 3, k7 = kr2 & 7;
#pragma unroll
        for (int j = 0; j < 8; j++) {
          int row = mg * 8 + j;
          int xr = (row ^ (row >> 2)) & 3;
          ushort pr[2] = {v0[j], v1[j]};
          *(uint*)&As[row * 32 + (sl0 ^ xr) * 8 + k7] = *(uint*)pr;
        }
      }
      // Bs: 128 rows via direct-to-LDS DMA (2 per wave)
#pragma unroll
      for (int it = 0; it < 2; it++) {
        int rb = wave * 16 + it * 64;
        int row = rb + srow;
        int xr = (row ^ (row >> 2)) & 3;
        gload16(&W[(size_t)(n0 + row) * 256 + kc + (slot ^ xr) * 8],
                &Bs[rb * 32]);
      }
      __syncthreads();

      s8v a[4], bfr[4];
#pragma unroll
      for (int mi = 0; mi < 4; mi++)
        a[mi] = *(const s8v*)&As[(wm + mi * 16 + tm) * 32 + (quad ^ xorv) * 8];
#pragma unroll
      for (int ni = 0; ni < 4; ni++)
        bfr[ni] =
            *(const s8v*)&Bs[(wn + ni * 16 + tm) * 32 + (quad ^ xorv) * 8];
#pragma unroll
      for (int mi = 0; mi < 4; mi++)
#pragma unroll
        for (int ni = 0; ni < 4; ni++)
          acc[mi][ni] = __builtin_amdgcn_mfma_f32_16x16x32_bf16(
              a[mi], bfr[ni], acc[mi][ni], 0, 0, 0);
    }

    // C/D layout: col = lane&15, row = quad*4 + reg
#pragma unroll
    for (int mi = 0; mi < 4; mi++) {
#pragma unroll
      for (int ni = 0; ni < 4; ni++) {
        int col = n0 + wn + ni * 16 + tm;
        float bv = bias[col];
#pragma unroll
        for (int r = 0; r < 4; r++) {
          int row = m0 + wm + mi * 16 + quad * 4 + r;
          out[(size_t)row * 256 + col] = f2bf(acc[mi][ni][r] + bv);
        }
      }
    }
    return;
  }

  // ---------------- pooled q/k linear path (K-chunk 32) ----------------
  {
    int t = bx - 1024;            // 0..255
    int z = t & 3;
    int n0 = ((t >> 2) & 3) * 64;
    int b = t >> 4;

    ushort* Ah = pool;            // 64 x 36
    ushort* Al = pool + 2304;
    ushort* Wh = pool + 4608;
    ushort* Wl = pool + 6912;

    const float* At = z == 0 ? s0 : z == 1 ? s1 : z == 2 ? s2 : s3;
    const ushort* Whp = whl + (size_t)z * 131072;
    const ushort* Wlp = Whp + 65536;
    const float* biasz = z == 0 ? b0 : z == 1 ? b1 : z == 2 ? b2 : b3;
    float* Cout = z == 0 ? d0 : z == 1 ? d1 : z == 2 ? d2 : d3;

    const float* Ab = At + (size_t)b * 256 * 64;  // [k][m], m contiguous

    int wm = (wave & 1) * 32, wn = (wave >> 1) * 32;

    f4v acc[2][2] = {};

    for (int kc = 0; kc < 256; kc += 32) {
      __syncthreads();
      // stage A: 64m x 32k fp32 -> hi/lo transpose (one pass, 256 threads)
      {
        int mq = tid & 15, kp = tid >> 4;  // kp 0..15
        int k0 = kp * 2, m0 = mq * 4;
        float4 v0 = *(const float4*)&Ab[(size_t)(kc + k0) * 64 + m0];
        float4 v1 = *(const float4*)&Ab[(size_t)(kc + k0 + 1) * 64 + m0];
        float f0[4] = {v0.x, v0.y, v0.z, v0.w};
        float f1[4] = {v1.x, v1.y, v1.z, v1.w};
#pragma unroll
        for (int j = 0; j < 4; j++) {
          ushort h0 = f2bf(f0[j]), h1 = f2bf(f1[j]);
          ushort l0 = f2bf(f0[j] - bf2f(h0)), l1 = f2bf(f1[j] - bf2f(h1));
          ushort ph[2] = {h0, h1};
          ushort pl[2] = {l0, l1};
          *(uint*)&Ah[(m0 + j) * 36 + k0] = *(uint*)ph;
          *(uint*)&Al[(m0 + j) * 36 + k0] = *(uint*)pl;
        }
      }
      // stage W: 64n x 32k hi and lo (8B stores; 72B row stride is 8B-aligned)
      {
        int nr = tid >> 2, k8 = (tid & 3) * 8;
        u8v vh = *(const u8v*)&Whp[(size_t)(n0 + nr) * 256 + kc + k8];
        u8v vl = *(const u8v*)&Wlp[(size_t)(n0 + nr) * 256 + kc + k8];
        union { u8v v; unsigned long long u[2]; } ch, cl;
        ch.v = vh; cl.v = vl;
        *(unsigned long long*)&Wh[nr * 36 + k8] = ch.u[0];
        *(unsigned long long*)&Wh[nr * 36 + k8 + 4] = ch.u[1];
        *(unsigned long long*)&Wl[nr * 36 + k8] = cl.u[0];
        *(unsigned long long*)&Wl[nr * 36 + k8 + 4] = cl.u[1];
      }
      __syncthreads();

      s8v ah[2], al[2], bh[2], bl[2];
#pragma unroll
      for (int mi = 0; mi < 2; mi++) {
        int idx = (wm + mi * 16 + tm) * 36 + quad * 8;
        union { s8v v; unsigned long long u[2]; } th, tl;
        th.u[0] = *(const unsigned long long*)&Ah[idx];
        th.u[1] = *(const unsigned long long*)&Ah[idx + 4];
        tl.u[0] = *(const unsigned long long*)&Al[idx];
        tl.u[1] = *(const unsigned long long*)&Al[idx + 4];
        ah[mi] = th.v;
        al[mi] = tl.v;
      }
#pragma unroll
      for (int ni = 0; ni < 2; ni++) {
        int idx = (wn + ni * 16 + tm) * 36 + quad * 8;
        union { s8v v; unsigned long long u[2]; } th, tl;
        th.u[0] = *(const unsigned long long*)&Wh[idx];
        th.u[1] = *(const unsigned long long*)&Wh[idx + 4];
        tl.u[0] = *(const unsigned long long*)&Wl[idx];
        tl.u[1] = *(const unsigned long long*)&Wl[idx + 4];
        bh[ni] = th.v;
        bl[ni] = tl.v;
      }
#pragma unroll
      for (int mi = 0; mi < 2; mi++)
#pragma unroll
        for (int ni = 0; ni < 2; ni++) {
          acc[mi][ni] = __builtin_amdgcn_mfma_f32_16x16x32_bf16(
              ah[mi], bh[ni], acc[mi][ni], 0, 0, 0);
          acc[mi][ni] = __builtin_amdgcn_mfma_f32_16x16x32_bf16(
              ah[mi], bl[ni], acc[mi][ni], 0, 0, 0);
          acc[mi][ni] = __builtin_amdgcn_mfma_f32_16x16x32_bf16(
              al[mi], bh[ni], acc[mi][ni], 0, 0, 0);
        }
    }

#pragma unroll
    for (int mi = 0; mi < 2; mi++) {
#pragma unroll
      for (int ni = 0; ni < 2; ni++) {
        int n = n0 + wn + ni * 16 + tm;
        float bv = biasz[n];
#pragma unroll
        for (int r = 0; r < 4; r++) {
          int m = b * 64 + wm + mi * 16 + quad * 4 + r;
          Cout[(size_t)m * 256 + n] = acc[mi][ni][r] + bv;
        }
      }
    }
  }
}

// ---------------------------------------------------------------------------
// K3: attention softmax, both axes fused. Block = (set,b,hd): stages q/k
// once, loops all 16 row-quads. High occupancy, attn is L2/L3-resident for
// the consumers (fusing this into k_av/k_rw measured WORSE: low-occupancy
// serial recompute x8 > cheap cache re-reads).
// ---------------------------------------------------------------------------
__global__ __launch_bounds__(256) void k_attn(
    const float* __restrict__ qh, const float* __restrict__ kh,
    const float* __restrict__ Bh, float* __restrict__ ah,
    const float* __restrict__ qw, const float* __restrict__ kw,
    const float* __restrict__ Bw, float* __restrict__ aw, float scale) {
  __shared__ float qs[64 * 33];
  __shared__ float ks[64 * 33];

  int bx = blockIdx.x;             // 256 blocks
  int setw = bx >> 7;
  int rem = bx & 127;
  int hd = rem & 7, b = rem >> 3;
  int tid = threadIdx.x;
  int wave = tid >> 6, lane = tid & 63;

  const float* q = setw ? qw : qh;
  const float* k = setw ? kw : kh;
  const float* Bb = setw ? Bw : Bh;
  float* attn = setw ? aw : ah;

#pragma unroll
  for (int it = 0; it < 8; it++) {
    int f = tid + it * 256;
    int j = f >> 5, d = f & 31;
    size_t src = (size_t)(b * 64 + j) * 256 + hd * 32 + d;
    qs[j * 33 + d] = q[src];
    ks[j * 33 + d] = k[src];
  }
  __syncthreads();

  const float* Bp = Bb + (size_t)(hd * 64) * 64;
  float* ap = attn + (size_t)((b * 8 + hd) * 64) * 64;
  int j = lane;
  for (int ig = 0; ig < 16; ig++) {
    int i = ig * 4 + wave;
    float dot = 0.f;
#pragma unroll
    for (int d = 0; d < 32; d++) dot += qs[i * 33 + d] * ks[j * 33 + d];
    float logit = dot * scale + Bp[i * 64 + j];
    float mx = logit;
#pragma unroll
    for (int off = 32; off > 0; off >>= 1)
      mx = fmaxf(mx, __shfl_xor(mx, off, 64));
    float e = __expf(logit - mx);
    float sum = e;
#pragma unroll
    for (int off = 32; off > 0; off >>= 1) sum += __shfl_xor(sum, off, 64);
    ap[i * 64 + j] = e / sum;
  }
}

// ---------------------------------------------------------------------------
// K5a (MFMA): r1[b][hd][h=64][c=2048] = attn_h[64x64] @ vlinT[64][2048]
// ---------------------------------------------------------------------------
__global__ __launch_bounds__(256) void k_av(const float* __restrict__ attn,
                                            const ushort* __restrict__ vlin,
                                            ushort* __restrict__ r1) {
  __shared__ __align__(16) ushort Ah[64 * 68];   // attn hi  [i][j]
  __shared__ __align__(16) ushort Al[64 * 68];   // attn lo  [i][j]
  __shared__ __align__(16) ushort Bt[256 * 68];  // vlin^T   [c][j]

  int bx = blockIdx.x;
  int nt = bx & 7, hd = (bx >> 3) & 7, b = bx >> 6;
  int n0 = nt * 256;
  int tid = threadIdx.x;
  int lane = tid & 63, wave = tid >> 6;

  const float* ap = attn + (size_t)(b * 8 + hd) * 4096;
  {
    int i = tid >> 2;          // row 0..63
    int j0 = (tid & 3) * 16;   // 16 cols per thread
#pragma unroll
    for (int p = 0; p < 4; p++) {
      float4 v = *(const float4*)&ap[i * 64 + j0 + p * 4];
      float f_[4] = {v.x, v.y, v.z, v.w};
      ushort ph[4], pl[4];
#pragma unroll
      for (int q = 0; q < 4; q++) {
        ph[q] = f2bf(f_[q]);
        pl[q] = f2bf(f_[q] - bf2f(ph[q]));
      }
      *(uint2*)&Ah[i * 68 + j0 + p * 4] = *(uint2*)ph;
      *(uint2*)&Al[i * 68 + j0 + p * 4] = *(uint2*)pl;
    }
  }
  {
#pragma unroll
    for (int p = 0; p < 4; p++) {
      int task = tid + p * 256;   // 0..1023
      int jp = task & 31;         // j-pair index
      int cc = task >> 5;         // c-chunk 0..31 (8 dv each)
      int j = jp * 2;
      int c = cc * 8;             // local col base
      int gcol = n0 + c;
      int w = gcol >> 5, dv = gcol & 31;
      const ushort* vp =
          &vlin[(size_t)(b * 4096 + j * 64 + w) * 256 + hd * 32 + dv];
      u8v v0 = *(const u8v*)vp;
      u8v v1 = *(const u8v*)(vp + 64 * 256);  // next j
#pragma unroll
      for (int q = 0; q < 8; q++) {
        ushort pr[2] = {(ushort)v0[q], (ushort)v1[q]};
        *(uint*)&Bt[(c + q) * 68 + j] = *(uint*)pr;
      }
    }
  }
  __syncthreads();

  int tm = lane & 15, quad = lane >> 4;
  int wn = wave * 64;
  f4v acc[4][4] = {};
#pragma unroll
  for (int kc = 0; kc < 64; kc += 32) {
    s8v ah_[4], al_[4], bb[4];
#pragma unroll
    for (int mi = 0; mi < 4; mi++) {
      int idx = (mi * 16 + tm) * 68 + kc + quad * 8;
      union { s8v v; unsigned long long u[2]; } th, tl;
      th.u[0] = *(const unsigned long long*)&Ah[idx];
      th.u[1] = *(const unsigned long long*)&Ah[idx + 4];
      tl.u[0] = *(const unsigned long long*)&Al[idx];
      tl.u[1] = *(const unsigned long long*)&Al[idx + 4];
      ah_[mi] = th.v;
      al_[mi] = tl.v;
    }
#pragma unroll
    for (int ni = 0; ni < 4; ni++) {
      int idx = (wn + ni * 16 + tm) * 68 + kc + quad * 8;
      union { s8v v; unsigned long long u[2]; } tb;
      tb.u[0] = *(const unsigned long long*)&Bt[idx];
      tb.u[1] = *(const unsigned long long*)&Bt[idx + 4];
      bb[ni] = tb.v;
    }
#pragma unroll
    for (int mi = 0; mi < 4; mi++)
#pragma unroll
      for (int ni = 0; ni < 4; ni++) {
        acc[mi][ni] = __builtin_amdgcn_mfma_f32_16x16x32_bf16(
            ah_[mi], bb[ni], acc[mi][ni], 0, 0, 0);
        acc[mi][ni] = __builtin_amdgcn_mfma_f32_16x16x32_bf16(
            al_[mi], bb[ni], acc[mi][ni], 0, 0, 0);
      }
  }

  ushort* rp = r1 + (size_t)(b * 8 + hd) * 64 * 2048;
#pragma unroll
  for (int mi = 0; mi < 4; mi++) {
#pragma unroll
    for (int ni = 0; ni < 4; ni++) {
      int col = n0 + wn + ni * 16 + tm;
#pragma unroll
      for (int r = 0; r < 4; r++) {
        int row = mi * 16 + quad * 4 + r;
        rp[(size_t)row * 2048 + col] = f2bf(acc[mi][ni][r]);
      }
    }
  }
}

// ---------------------------------------------------------------------------
// K5b (MFMA): yT[(b*4096+h*64+w')][hd*32+dv]
//               = sum_w r1[b,hd,h,w*32+dv] * attnw[w][w']
// ---------------------------------------------------------------------------
__global__ __launch_bounds__(256) void k_rw(const ushort* __restrict__ r1,
                                            const float* __restrict__ attnw,
                                            ushort* __restrict__ yT) {
  __shared__ __align__(16) ushort As[8 * 2180];   // 34880 B
  __shared__ __align__(16) ushort Wh[64 * 68];    //  8704 B  (hi)
  __shared__ __align__(16) ushort Wl[64 * 68];    //  8704 B  (lo)

  int bx = blockIdx.x;
  int ht = bx & 7, hd = (bx >> 3) & 7, b = bx >> 6;
  int tid = threadIdx.x;
  int lane = tid & 63, wave = tid >> 6;

  {
    int h = tid >> 5;                // 0..7
    int t = tid & 31;
    const ushort* rp =
        r1 + (size_t)((b * 8 + hd) * 64 + ht * 8 + h) * 2048;
#pragma unroll
    for (int i = 0; i < 4; i++) {
      int chunk = t + 32 * i;        // 0..127
      int w = (chunk >> 2) * 2;      // even w
      int dv0 = (chunk & 3) * 8;
      u8v v0 = *(const u8v*)&rp[w * 32 + dv0];
      u8v v1 = *(const u8v*)&rp[(w + 1) * 32 + dv0];
#pragma unroll
      for (int j = 0; j < 8; j++) {
        ushort pr[2] = {(ushort)v0[j], (ushort)v1[j]};
        *(uint*)&As[h * 2180 + (dv0 + j) * 68 + w] = *(uint*)pr;
      }
    }
  }
  {
    const float* ap = attnw + (size_t)(b * 8 + hd) * 4096;
#pragma unroll
    for (int p = 0; p < 4; p++) {
      int w = (tid >> 4) + p * 16;
      int wq = (tid & 15) * 4;
      float4 v = *(const float4*)&ap[w * 64 + wq];
      float f_[4] = {v.x, v.y, v.z, v.w};
#pragma unroll
      for (int j = 0; j < 4; j++) {
        ushort hi = f2bf(f_[j]);
        Wh[(wq + j) * 68 + w] = hi;
        Wl[(wq + j) * 68 + w] = f2bf(f_[j] - bf2f(hi));
      }
    }
  }
  __syncthreads();

  int tm = lane & 15, quad = lane >> 4;
  int h0 = wave * 2;
  f4v acc[4][4] = {};
#pragma unroll
  for (int kc = 0; kc < 64; kc += 32) {
    s8v a[4], bh[4], bl[4];
#pragma unroll
    for (int mi = 0; mi < 4; mi++) {
      int h = h0 + (mi >> 1);
      int dv = (mi & 1) * 16 + tm;
      int idx = h * 2180 + dv * 68 + kc + quad * 8;
      union { s8v v; unsigned long long u[2]; } t_;
      t_.u[0] = *(const unsigned long long*)&As[idx];
      t_.u[1] = *(const unsigned long long*)&As[idx + 4];
      a[mi] = t_.v;
    }
#pragma unroll
    for (int ni = 0; ni < 4; ni++) {
      int idx = (ni * 16 + tm) * 68 + kc + quad * 8;
      union { s8v v; unsigned long long u[2]; } th, tl;
      th.u[0] = *(const unsigned long long*)&Wh[idx];
      th.u[1] = *(const unsigned long long*)&Wh[idx + 4];
      tl.u[0] = *(const unsigned long long*)&Wl[idx];
      tl.u[1] = *(const unsigned long long*)&Wl[idx + 4];
      bh[ni] = th.v;
      bl[ni] = tl.v;
    }
#pragma unroll
    for (int mi = 0; mi < 4; mi++)
#pragma unroll
      for (int ni = 0; ni < 4; ni++) {
        acc[mi][ni] = __builtin_amdgcn_mfma_f32_16x16x32_bf16(
            a[mi], bh[ni], acc[mi][ni], 0, 0, 0);
        acc[mi][ni] = __builtin_amdgcn_mfma_f32_16x16x32_bf16(
            a[mi], bl[ni], acc[mi][ni], 0, 0, 0);
      }
  }

#pragma unroll
  for (int mi = 0; mi < 4; mi++) {
    int h = ht * 8 + h0 + (mi >> 1);
    int dv0 = (mi & 1) * 16 + quad * 4;
#pragma unroll
    for (int ni = 0; ni < 4; ni++) {
      int wp = ni * 16 + tm;
      ushort pk[4];
#pragma unroll
      for (int r = 0; r < 4; r++) pk[r] = f2bf(acc[mi][ni][r]);
      *(uint2*)&yT[(size_t)(b * 4096 + h * 64 + wp) * 256 + hd * 32 + dv0] =
          *(uint2*)pk;
    }
  }
}

// ---------------------------------------------------------------------------
// K_out: final GEMM, 128m x 256n (full-N: A read once), fp32 out + bias.
// A = yT [M][256] bf16 k-contig; W = fc_o bf16 [n][k]. gload16 staging.
// ---------------------------------------------------------------------------
__global__ __launch_bounds__(256) void k_out(const ushort* __restrict__ A,
                                             const ushort* __restrict__ W,
                                             const float* __restrict__ bias,
                                             float* __restrict__ out) {
  __shared__ __align__(16) ushort As[128 * 32];
  __shared__ __align__(16) ushort Bs[256 * 32];

  int m0 = blockIdx.x * 128;
  int tid = threadIdx.x;
  int lane = tid & 63, wave = tid >> 6;
  int wm = (wave & 1) * 64, wn = (wave >> 1) * 128;
  int tm = lane & 15, quad = lane >> 4;
  int xorv = (tm ^ (tm >> 2)) & 3;
  int srow = lane >> 2;
  int slot = lane & 3;

  const ushort* Abase = A + (size_t)m0 * 256;

  f4v acc[4][8] = {};

  for (int kc = 0; kc < 256; kc += 32) {
    __syncthreads();
#pragma unroll
    for (int it = 0; it < 2; it++) {
      int rb = wave * 16 + it * 64;
      int row = rb + srow;
      int xr = (row ^ (row >> 2)) & 3;
      gload16(&Abase[(size_t)row * 256 + kc + (slot ^ xr) * 8], &As[rb * 32]);
    }
#pragma unroll
    for (int it = 0; it < 4; it++) {
      int rb = wave * 16 + it * 64;
      int row = rb + srow;
      int xr = (row ^ (row >> 2)) & 3;
      gload16(&W[(size_t)row * 256 + kc + (slot ^ xr) * 8], &Bs[rb * 32]);
    }
    __syncthreads();

    s8v a[4];
#pragma unroll
    for (int mi = 0; mi < 4; mi++)
      a[mi] = *(const s8v*)&As[(wm + mi * 16 + tm) * 32 + (quad ^ xorv) * 8];
#pragma unroll
    for (int ni = 0; ni < 8; ni++) {
      s8v bfr = *(const s8v*)&Bs[(wn + ni * 16 + tm) * 32 + (quad ^ xorv) * 8];
#pragma unroll
      for (int mi = 0; mi < 4; mi++)
        acc[mi][ni] = __builtin_amdgcn_mfma_f32_16x16x32_bf16(
            a[mi], bfr, acc[mi][ni], 0, 0, 0);
    }
  }

  // C/D layout: col = lane&15, row = quad*4 + reg
#pragma unroll
  for (int mi = 0; mi < 4; mi++) {
#pragma unroll
    for (int ni = 0; ni < 8; ni++) {
      int col = wn + ni * 16 + tm;
      float bv = bias[col];
#pragma unroll
      for (int r = 0; r < 4; r++) {
        int row = m0 + wm + mi * 16 + quad * 4 + r;
        out[(size_t)row * 256 + col] = acc[mi][ni][r] + bv;
      }
    }
  }
}

// ---------------------------------------------------------------------------
extern "C" void kernel_launch(void* const* d_in, const int* in_sizes, int n_in,
                              void* d_out, int out_size, void* d_ws,
                              size_t ws_size, hipStream_t stream) {
  const float* x      = (const float*)d_in[0];
  const float* dwqh_w = (const float*)d_in[1];
  const float* dwqh_b = (const float*)d_in[2];
  const float* fcqh_w = (const float*)d_in[3];
  const float* fcqh_b = (const float*)d_in[4];
  const float* dwkh_w = (const float*)d_in[5];
  const float* dwkh_b = (const float*)d_in[6];
  const float* fckh_w = (const float*)d_in[7];
  const float* fckh_b = (const float*)d_in[8];
  const float* Bh     = (const float*)d_in[9];
  const float* dwv_w  = (const float*)d_in[10];
  const float* dwv_b  = (const float*)d_in[11];
  const float* fcv_w  = (const float*)d_in[12];
  const float* fcv_b  = (const float*)d_in[13];
  const float* dwqw_w = (const float*)d_in[14];
  const float* dwqw_b = (const float*)d_in[15];
  const float* fcqw_w = (const float*)d_in[16];
  const float* fcqw_b = (const float*)d_in[17];
  const float* dwkw_w = (const float*)d_in[18];
  const float* dwkw_b = (const float*)d_in[19];
  const float* fckw_w = (const float*)d_in[20];
  const float* fckw_b = (const float*)d_in[21];
  const float* Bw     = (const float*)d_in[22];
  const float* fco_w  = (const float*)d_in[23];
  const float* fco_b  = (const float*)d_in[24];

  char* base = (char*)d_ws;
  ushort* P1 = (ushort*)(base);                  // convV, later r1
  ushort* P2 = (ushort*)(base + 33554432);       // yT
  ushort* P3 = (ushort*)(base + 67108864);       // vlin
  ushort* whl  = (ushort*)(base + 100663296);    // 4 x (hi|lo) 65536 bf16
  ushort* wv_bf = (ushort*)(base + 101711872);   // 2 x 65536 bf16
  float* qhm = (float*)(base + 101974016);
  float* khm = qhm + 262144;
  float* qwm = khm + 262144;
  float* kwm = qwm + 262144;
  float* qhl = kwm + 262144;
  float* khl = qhl + 262144;
  float* qwl = khl + 262144;
  float* kwl = qwl + 262144;
  float* ah  = kwl + 262144;                     // 524288
  float* awt = ah + 524288;                      // 524288
  if (ws_size < 115000000ull) return;

  const float scale = 0.17677669529663687f;  // 32^-0.5

  k_conv<<<5632, 256, 0, stream>>>(x, dwqh_w, dwqh_b, dwkh_w, dwkh_b, dwv_w,
                                   dwv_b, dwqw_w, dwqw_b, dwkw_w, dwkw_b,
                                   fcqh_w, fckh_w, fcqw_w, fckw_w, fcv_w,
                                   fco_w, whl, wv_bf, P1,
                                   qhm, khm, qwm, kwm);
  k_mmv<<<1280, 256, 0, stream>>>(P1, wv_bf, fcv_b, P3,
                                  qhm, khm, qwm, kwm, whl, fcqh_b, fckh_b,
                                  fcqw_b, fckw_b, qhl, khl, qwl, kwl);
  k_attn<<<256, 256, 0, stream>>>(qhl, khl, Bh, ah, qwl, kwl, Bw, awt, scale);
  k_av<<<1024, 256, 0, stream>>>(ah, P3, P1);
  k_rw<<<1024, 256, 0, stream>>>(P1, awt, P2);
  k_out<<<512, 256, 0, stream>>>(P2, wv_bf + 65536, fco_b, (float*)d_out);
}

// Round 11
// 267.360 us; speedup vs baseline: 1.1291x; 1.0303x over previous
//
#include <hip/hip_runtime.h>
#include <hip/hip_bf16.h>

typedef float f4v __attribute__((ext_vector_type(4)));
typedef short s8v __attribute__((ext_vector_type(8)));
typedef unsigned short u8v __attribute__((ext_vector_type(8)));

__device__ __forceinline__ float bf2f(ushort u) {
  union { unsigned int i; float f; } c; c.i = ((unsigned int)u) << 16;
  return c.f;
}
__device__ __forceinline__ ushort f2bf(float f) {
  union { ushort s; __hip_bfloat16 h; } c; c.h = __float2bfloat16(f);
  return c.s;
}
// Direct global->LDS 16B DMA. lds base must be wave-uniform; lane l writes
// lds + l*16. Source address is per-lane.
__device__ __forceinline__ void gload16(const ushort* g, ushort* l) {
  __builtin_amdgcn_global_load_lds(
      (const __attribute__((address_space(1))) unsigned int*)g,
      (__attribute__((address_space(3))) unsigned int*)l, 16, 0, 0);
}

// ---------------------------------------------------------------------------
// K1 (+prep fold): bx<4096: per (b,c) conv plane work.
// bx in [4096,5120): cast four fp32 q/k weights [o][k] to bf16 hi/lo pairs.
// bx in [5120,5632): cast fc_v|fc_o to bf16 [n][k].
// ---------------------------------------------------------------------------
__global__ __launch_bounds__(256) void k_conv(
    const float* __restrict__ x,
    const float* __restrict__ wqh, const float* __restrict__ bqh,
    const float* __restrict__ wkh, const float* __restrict__ bkh,
    const float* __restrict__ wv,  const float* __restrict__ bv,
    const float* __restrict__ wqw, const float* __restrict__ bqw,
    const float* __restrict__ wkw, const float* __restrict__ bkw,
    const float* __restrict__ fq0, const float* __restrict__ fq1,
    const float* __restrict__ fq2, const float* __restrict__ fq3,
    const float* __restrict__ fwv, const float* __restrict__ fwo,
    ushort* __restrict__ whl, ushort* __restrict__ wbf,
    ushort* __restrict__ convV,
    float* __restrict__ qhm, float* __restrict__ khm,
    float* __restrict__ qwm, float* __restrict__ kwm) {
  __shared__ float xs[68 * 68];
  __shared__ float wl[5][9];
  __shared__ float bl[5];

  int bx = blockIdx.x;
  int tid = threadIdx.x;

  if (bx >= 4096) {
    int pb = bx - 4096;
    if (pb < 1024) {
      int mat = pb >> 8;
      int i = (pb & 255) * 256 + tid;
      const float* p = mat == 0 ? fq0 : mat == 1 ? fq1 : mat == 2 ? fq2 : fq3;
      float f = p[i];
      ushort hi = f2bf(f);
      ushort lo = f2bf(f - bf2f(hi));
      whl[(size_t)mat * 131072 + i] = hi;
      whl[(size_t)mat * 131072 + 65536 + i] = lo;
    } else {
      int idx = (pb - 1024) * 256 + tid;  // 0..131071
      const float* src = (idx >> 16) ? fwo : fwv;
      wbf[idx] = f2bf(src[idx & 65535]);
    }
    return;
  }

  int b = bx >> 8;
  int c = bx & 255;
  int lane = tid & 63, wave = tid >> 6;

  const float* xp = x + (size_t)(b * 256 + c) * 4096;
#pragma unroll
  for (int i = 0; i < 4; i++) {
    int flat = tid + i * 256;          // 0..1023
    int r = flat >> 4, c4 = (flat & 15) * 4;
    float4 v = *(const float4*)(xp + r * 64 + c4);
    *(float4*)&xs[(r + 1) * 68 + 4 + c4] = v;
  }
  if (tid < 72) { xs[tid] = 0.f; xs[65 * 68 + tid] = 0.f; }
  if (tid >= 72 && tid < 200) {
    int t = tid - 72;
    int pr = (t & 63) + 1, side = t >> 6;
    xs[pr * 68 + (side ? 68 : 3)] = 0.f;
  }
  if (tid >= 200 && tid < 245) {
    int t = tid - 200;
    int cw = t / 9, wi = t % 9;
    const float* wp = cw == 0 ? wqh : cw == 1 ? wkh : cw == 2 ? wv
                    : cw == 3 ? wqw : wkw;
    wl[cw][wi] = wp[c * 9 + wi];
  } else if (tid >= 245 && tid < 250) {
    int cw = tid - 245;
    const float* bp = cw == 0 ? bqh : cw == 1 ? bkh : cw == 2 ? bv
                    : cw == 3 ? bqw : bkw;
    bl[cw] = bp[c];
  }
  __syncthreads();

  // ---- v-conv: wave handles rows h0..h0+15, lane = output col ----
  {
    int w = lane;
    int h0 = wave * 16;
    float v0 = wl[2][0], v1 = wl[2][1], v2 = wl[2][2];
    float v3 = wl[2][3], v4 = wl[2][4], v5 = wl[2][5];
    float v6 = wl[2][6], v7 = wl[2][7], v8 = wl[2][8];
    float bvv = bl[2];
    float a00 = xs[h0 * 68 + 3 + w], a01 = xs[h0 * 68 + 4 + w],
          a02 = xs[h0 * 68 + 5 + w];
    float a10 = xs[(h0 + 1) * 68 + 3 + w], a11 = xs[(h0 + 1) * 68 + 4 + w],
          a12 = xs[(h0 + 1) * 68 + 5 + w];
    ushort* cp = convV + (size_t)(b * 256 + c) * 4096 + h0 * 64 + w;
#pragma unroll
    for (int i = 0; i < 16; i++) {
      int pr = h0 + i + 2;
      float a20 = xs[pr * 68 + 3 + w];
      float a21 = xs[pr * 68 + 4 + w];
      float a22 = xs[pr * 68 + 5 + w];
      float acc = bvv;
      acc += a00 * v0 + a01 * v1 + a02 * v2;
      acc += a10 * v3 + a11 * v4 + a12 * v5;
      acc += a20 * v6 + a21 * v7 + a22 * v8;
      cp[i * 64] = f2bf(acc);
      a00 = a10; a01 = a11; a02 = a12;
      a10 = a20; a11 = a21; a12 = a22;
    }
  }

  // ---- pooled means from linearity: wave0 rows, wave1 cols ----
  if (wave == 0) {
    float rs = 0.f, e0 = 0.f, e1 = 0.f;
    const float* rowp = &xs[(lane + 1) * 68 + 4];
#pragma unroll
    for (int i = 0; i < 16; i++) {
      float4 v = *(const float4*)(rowp + i * 4);
      rs += (v.x + v.y) + (v.z + v.w);
      if (i == 0) e0 = v.x;
      if (i == 15) e1 = v.w;
    }
    float rsP = __shfl(rs, lane - 1, 64); rsP = (lane == 0) ? 0.f : rsP;
    float rsN = __shfl(rs, lane + 1, 64); rsN = (lane == 63) ? 0.f : rsN;
    float e0P = __shfl(e0, lane - 1, 64); e0P = (lane == 0) ? 0.f : e0P;
    float e0N = __shfl(e0, lane + 1, 64); e0N = (lane == 63) ? 0.f : e0N;
    float e1P = __shfl(e1, lane - 1, 64); e1P = (lane == 0) ? 0.f : e1P;
    float e1N = __shfl(e1, lane + 1, 64); e1N = (lane == 63) ? 0.f : e1N;
    float RS[3] = {rsP, rs, rsN};
    float E0[3] = {e0P, e0, e0N};
    float E1[3] = {e1P, e1, e1N};
    float vq = 0.f, vk = 0.f;
#pragma unroll
    for (int ky = 0; ky < 3; ky++) {
      vq += (wl[0][ky * 3] + wl[0][ky * 3 + 1] + wl[0][ky * 3 + 2]) * RS[ky]
            - wl[0][ky * 3] * E1[ky] - wl[0][ky * 3 + 2] * E0[ky];
      vk += (wl[1][ky * 3] + wl[1][ky * 3 + 1] + wl[1][ky * 3 + 2]) * RS[ky]
            - wl[1][ky * 3] * E1[ky] - wl[1][ky * 3 + 2] * E0[ky];
    }
    qhm[(size_t)(b * 256 + c) * 64 + lane] = vq * (1.f / 64.f) + bl[0];
    khm[(size_t)(b * 256 + c) * 64 + lane] = vk * (1.f / 64.f) + bl[1];
  } else if (wave == 1) {
    float cs = 0.f, f0 = 0.f, f1 = 0.f;
#pragma unroll
    for (int r = 0; r < 64; r++) {
      float v = xs[(r + 1) * 68 + 4 + lane];
      cs += v;
      if (r == 0) f0 = v;
      if (r == 63) f1 = v;
    }
    float csP = __shfl(cs, lane - 1, 64); csP = (lane == 0) ? 0.f : csP;
    float csN = __shfl(cs, lane + 1, 64); csN = (lane == 63) ? 0.f : csN;
    float f0P = __shfl(f0, lane - 1, 64); f0P = (lane == 0) ? 0.f : f0P;
    float f0N = __shfl(f0, lane + 1, 64); f0N = (lane == 63) ? 0.f : f0N;
    float f1P = __shfl(f1, lane - 1, 64); f1P = (lane == 0) ? 0.f : f1P;
    float f1N = __shfl(f1, lane + 1, 64); f1N = (lane == 63) ? 0.f : f1N;
    float CS[3] = {csP, cs, csN};
    float F0[3] = {f0P, f0, f0N};
    float F1[3] = {f1P, f1, f1N};
    float vq = 0.f, vk = 0.f;
#pragma unroll
    for (int kx = 0; kx < 3; kx++) {
      vq += (wl[3][kx] + wl[3][3 + kx] + wl[3][6 + kx]) * CS[kx]
            - wl[3][kx] * F1[kx] - wl[3][6 + kx] * F0[kx];
      vk += (wl[4][kx] + wl[4][3 + kx] + wl[4][6 + kx]) * CS[kx]
            - wl[4][kx] * F1[kx] - wl[4][6 + kx] * F0[kx];
    }
    qwm[(size_t)(b * 256 + c) * 64 + lane] = vq * (1.f / 64.f) + bl[3];
    kwm[(size_t)(b * 256 + c) * 64 + lane] = vk * (1.f / 64.f) + bl[4];
  }
}

// ---------------------------------------------------------------------------
// K2v (fused launch): bx<1024: vlin GEMM, 128m x 128n tile (acc[4][4], low
// VGPR), A transposed from convV [b][k=256][m=4096], B via global_load_lds.
// bx in [1024,1280): pooled q/k linear GEMM, K-chunks of 32 (18.4KB union).
// ---------------------------------------------------------------------------
__global__ __launch_bounds__(256) void k_mmv(
    const ushort* __restrict__ A, const ushort* __restrict__ W,
    const float* __restrict__ bias, ushort* __restrict__ out,
    const float* __restrict__ s0, const float* __restrict__ s1,
    const float* __restrict__ s2, const float* __restrict__ s3,
    const ushort* __restrict__ whl,
    const float* __restrict__ b0, const float* __restrict__ b1,
    const float* __restrict__ b2, const float* __restrict__ b3,
    float* __restrict__ d0, float* __restrict__ d1,
    float* __restrict__ d2, float* __restrict__ d3) {
  __shared__ __align__(16) ushort pool[9216];   // 18432 B union

  int bx = blockIdx.x;
  int tid = threadIdx.x;
  int lane = tid & 63, wave = tid >> 6;
  int tm = lane & 15, quad = lane >> 4;

  if (bx < 1024) {
    // ---------------- vlin GEMM path (128x128) ----------------
    ushort* As = pool;           // 128 rows x 32 k (64B rows)
    ushort* Bs = pool + 4096;    // 128 rows x 32 k

    int m0 = (bx >> 1) * 128;
    int n0 = (bx & 1) * 128;
    int wm = (wave & 1) * 64, wn = (wave >> 1) * 64;
    int xorv = (tm ^ (tm >> 2)) & 3;
    int srow = lane >> 2;
    int slot = lane & 3;

    const ushort* Abase = A + (size_t)(m0 >> 12) * (256 * 4096) + (m0 & 4095);

    f4v acc[4][4] = {};

    for (int kc = 0; kc < 256; kc += 32) {
      __syncthreads();
      // As: LDS transpose (register path), XOR slot layout
      {
        int kr2 = (tid & 15) * 2, mg = tid >> 4;
        u8v v0 = *(const u8v*)&Abase[(size_t)(kc + kr2) * 4096 + mg * 8];
        u8v v1 = *(const u8v*)&Abase[(size_t)(kc + kr2 + 1) * 4096 + mg * 8];
        int sl0 = kr2 >> 3, k7 = kr2 & 7;
#pragma unroll
        for (int j = 0; j < 8; j++) {
          int row = mg * 8 + j;
          int xr = (row ^ (row >> 2)) & 3;
          ushort pr[2] = {v0[j], v1[j]};
          *(uint*)&As[row * 32 + (sl0 ^ xr) * 8 + k7] = *(uint*)pr;
        }
      }
      // Bs: 128 rows via direct-to-LDS DMA (2 per wave)
#pragma unroll
      for (int it = 0; it < 2; it++) {
        int rb = wave * 16 + it * 64;
        int row = rb + srow;
        int xr = (row ^ (row >> 2)) & 3;
        gload16(&W[(size_t)(n0 + row) * 256 + kc + (slot ^ xr) * 8],
                &Bs[rb * 32]);
      }
      __syncthreads();

      s8v a[4], bfr[4];
#pragma unroll
      for (int mi = 0; mi < 4; mi++)
        a[mi] = *(const s8v*)&As[(wm + mi * 16 + tm) * 32 + (quad ^ xorv) * 8];
#pragma unroll
      for (int ni = 0; ni < 4; ni++)
        bfr[ni] =
            *(const s8v*)&Bs[(wn + ni * 16 + tm) * 32 + (quad ^ xorv) * 8];
#pragma unroll
      for (int mi = 0; mi < 4; mi++)
#pragma unroll
        for (int ni = 0; ni < 4; ni++)
          acc[mi][ni] = __builtin_amdgcn_mfma_f32_16x16x32_bf16(
              a[mi], bfr[ni], acc[mi][ni], 0, 0, 0);
    }

    // C/D layout: col = lane&15, row = quad*4 + reg
#pragma unroll
    for (int mi = 0; mi < 4; mi++) {
#pragma unroll
      for (int ni = 0; ni < 4; ni++) {
        int col = n0 + wn + ni * 16 + tm;
        float bv = bias[col];
#pragma unroll
        for (int r = 0; r < 4; r++) {
          int row = m0 + wm + mi * 16 + quad * 4 + r;
          out[(size_t)row * 256 + col] = f2bf(acc[mi][ni][r] + bv);
        }
      }
    }
    return;
  }

  // ---------------- pooled q/k linear path (K-chunk 32) ----------------
  {
    int t = bx - 1024;            // 0..255
    int z = t & 3;
    int n0 = ((t >> 2) & 3) * 64;
    int b = t >> 4;

    ushort* Ah = pool;            // 64 x 36
    ushort* Al = pool + 2304;
    ushort* Wh = pool + 4608;
    ushort* Wl = pool + 6912;

    const float* At = z == 0 ? s0 : z == 1 ? s1 : z == 2 ? s2 : s3;
    const ushort* Whp = whl + (size_t)z * 131072;
    const ushort* Wlp = Whp + 65536;
    const float* biasz = z == 0 ? b0 : z == 1 ? b1 : z == 2 ? b2 : b3;
    float* Cout = z == 0 ? d0 : z == 1 ? d1 : z == 2 ? d2 : d3;

    const float* Ab = At + (size_t)b * 256 * 64;  // [k][m], m contiguous

    int wm = (wave & 1) * 32, wn = (wave >> 1) * 32;

    f4v acc[2][2] = {};

    for (int kc = 0; kc < 256; kc += 32) {
      __syncthreads();
      // stage A: 64m x 32k fp32 -> hi/lo transpose (one pass, 256 threads)
      {
        int mq = tid & 15, kp = tid >> 4;  // kp 0..15
        int k0 = kp * 2, m0 = mq * 4;
        float4 v0 = *(const float4*)&Ab[(size_t)(kc + k0) * 64 + m0];
        float4 v1 = *(const float4*)&Ab[(size_t)(kc + k0 + 1) * 64 + m0];
        float f0[4] = {v0.x, v0.y, v0.z, v0.w};
        float f1[4] = {v1.x, v1.y, v1.z, v1.w};
#pragma unroll
        for (int j = 0; j < 4; j++) {
          ushort h0 = f2bf(f0[j]), h1 = f2bf(f1[j]);
          ushort l0 = f2bf(f0[j] - bf2f(h0)), l1 = f2bf(f1[j] - bf2f(h1));
          ushort ph[2] = {h0, h1};
          ushort pl[2] = {l0, l1};
          *(uint*)&Ah[(m0 + j) * 36 + k0] = *(uint*)ph;
          *(uint*)&Al[(m0 + j) * 36 + k0] = *(uint*)pl;
        }
      }
      // stage W: 64n x 32k hi and lo (8B stores; 72B row stride is 8B-aligned)
      {
        int nr = tid >> 2, k8 = (tid & 3) * 8;
        u8v vh = *(const u8v*)&Whp[(size_t)(n0 + nr) * 256 + kc + k8];
        u8v vl = *(const u8v*)&Wlp[(size_t)(n0 + nr) * 256 + kc + k8];
        union { u8v v; unsigned long long u[2]; } ch, cl;
        ch.v = vh; cl.v = vl;
        *(unsigned long long*)&Wh[nr * 36 + k8] = ch.u[0];
        *(unsigned long long*)&Wh[nr * 36 + k8 + 4] = ch.u[1];
        *(unsigned long long*)&Wl[nr * 36 + k8] = cl.u[0];
        *(unsigned long long*)&Wl[nr * 36 + k8 + 4] = cl.u[1];
      }
      __syncthreads();

      s8v ah[2], al[2], bh[2], bl[2];
#pragma unroll
      for (int mi = 0; mi < 2; mi++) {
        int idx = (wm + mi * 16 + tm) * 36 + quad * 8;
        union { s8v v; unsigned long long u[2]; } th, tl;
        th.u[0] = *(const unsigned long long*)&Ah[idx];
        th.u[1] = *(const unsigned long long*)&Ah[idx + 4];
        tl.u[0] = *(const unsigned long long*)&Al[idx];
        tl.u[1] = *(const unsigned long long*)&Al[idx + 4];
        ah[mi] = th.v;
        al[mi] = tl.v;
      }
#pragma unroll
      for (int ni = 0; ni < 2; ni++) {
        int idx = (wn + ni * 16 + tm) * 36 + quad * 8;
        union { s8v v; unsigned long long u[2]; } th, tl;
        th.u[0] = *(const unsigned long long*)&Wh[idx];
        th.u[1] = *(const unsigned long long*)&Wh[idx + 4];
        tl.u[0] = *(const unsigned long long*)&Wl[idx];
        tl.u[1] = *(const unsigned long long*)&Wl[idx + 4];
        bh[ni] = th.v;
        bl[ni] = tl.v;
      }
#pragma unroll
      for (int mi = 0; mi < 2; mi++)
#pragma unroll
        for (int ni = 0; ni < 2; ni++) {
          acc[mi][ni] = __builtin_amdgcn_mfma_f32_16x16x32_bf16(
              ah[mi], bh[ni], acc[mi][ni], 0, 0, 0);
          acc[mi][ni] = __builtin_amdgcn_mfma_f32_16x16x32_bf16(
              ah[mi], bl[ni], acc[mi][ni], 0, 0, 0);
          acc[mi][ni] = __builtin_amdgcn_mfma_f32_16x16x32_bf16(
              al[mi], bh[ni], acc[mi][ni], 0, 0, 0);
        }
    }

#pragma unroll
    for (int mi = 0; mi < 2; mi++) {
#pragma unroll
      for (int ni = 0; ni < 2; ni++) {
        int n = n0 + wn + ni * 16 + tm;
        float bv = biasz[n];
#pragma unroll
        for (int r = 0; r < 4; r++) {
          int m = b * 64 + wm + mi * 16 + quad * 4 + r;
          Cout[(size_t)m * 256 + n] = acc[mi][ni][r] + bv;
        }
      }
    }
  }
}

// ---------------------------------------------------------------------------
// K3: attention softmax, both axes fused. Block = (set,b,hd): stages q/k
// once, loops all 16 row-quads. High occupancy; attn stays L2/L3-resident
// for consumers (in-block recompute fusion measured WORSE in round 6).
// ---------------------------------------------------------------------------
__global__ __launch_bounds__(256) void k_attn(
    const float* __restrict__ qh, const float* __restrict__ kh,
    const float* __restrict__ Bh, float* __restrict__ ah,
    const float* __restrict__ qw, const float* __restrict__ kw,
    const float* __restrict__ Bw, float* __restrict__ aw, float scale) {
  __shared__ float qs[64 * 33];
  __shared__ float ks[64 * 33];

  int bx = blockIdx.x;             // 256 blocks
  int setw = bx >> 7;
  int rem = bx & 127;
  int hd = rem & 7, b = rem >> 3;
  int tid = threadIdx.x;
  int wave = tid >> 6, lane = tid & 63;

  const float* q = setw ? qw : qh;
  const float* k = setw ? kw : kh;
  const float* Bb = setw ? Bw : Bh;
  float* attn = setw ? aw : ah;

#pragma unroll
  for (int it = 0; it < 8; it++) {
    int f = tid + it * 256;
    int j = f >> 5, d = f & 31;
    size_t src = (size_t)(b * 64 + j) * 256 + hd * 32 + d;
    qs[j * 33 + d] = q[src];
    ks[j * 33 + d] = k[src];
  }
  __syncthreads();

  const float* Bp = Bb + (size_t)(hd * 64) * 64;
  float* ap = attn + (size_t)((b * 8 + hd) * 64) * 64;
  int j = lane;
  for (int ig = 0; ig < 16; ig++) {
    int i = ig * 4 + wave;
    float dot = 0.f;
#pragma unroll
    for (int d = 0; d < 32; d++) dot += qs[i * 33 + d] * ks[j * 33 + d];
    float logit = dot * scale + Bp[i * 64 + j];
    float mx = logit;
#pragma unroll
    for (int off = 32; off > 0; off >>= 1)
      mx = fmaxf(mx, __shfl_xor(mx, off, 64));
    float e = __expf(logit - mx);
    float sum = e;
#pragma unroll
    for (int off = 32; off > 0; off >>= 1) sum += __shfl_xor(sum, off, 64);
    ap[i * 64 + j] = e / sum;
  }
}

// ---------------------------------------------------------------------------
// K5a (MFMA): r1[b][hd][h=64][c=2048] = attn_h[64x64] @ vlinT[64][2048]
// ---------------------------------------------------------------------------
__global__ __launch_bounds__(256) void k_av(const float* __restrict__ attn,
                                            const ushort* __restrict__ vlin,
                                            ushort* __restrict__ r1) {
  __shared__ __align__(16) ushort Ah[64 * 68];   // attn hi  [i][j]
  __shared__ __align__(16) ushort Al[64 * 68];   // attn lo  [i][j]
  __shared__ __align__(16) ushort Bt[256 * 68];  // vlin^T   [c][j]

  int bx = blockIdx.x;
  int nt = bx & 7, hd = (bx >> 3) & 7, b = bx >> 6;
  int n0 = nt * 256;
  int tid = threadIdx.x;
  int lane = tid & 63, wave = tid >> 6;

  const float* ap = attn + (size_t)(b * 8 + hd) * 4096;
  {
    int i = tid >> 2;          // row 0..63
    int j0 = (tid & 3) * 16;   // 16 cols per thread
#pragma unroll
    for (int p = 0; p < 4; p++) {
      float4 v = *(const float4*)&ap[i * 64 + j0 + p * 4];
      float f_[4] = {v.x, v.y, v.z, v.w};
      ushort ph[4], pl[4];
#pragma unroll
      for (int q = 0; q < 4; q++) {
        ph[q] = f2bf(f_[q]);
        pl[q] = f2bf(f_[q] - bf2f(ph[q]));
      }
      *(uint2*)&Ah[i * 68 + j0 + p * 4] = *(uint2*)ph;
      *(uint2*)&Al[i * 68 + j0 + p * 4] = *(uint2*)pl;
    }
  }
  {
#pragma unroll
    for (int p = 0; p < 4; p++) {
      int task = tid + p * 256;   // 0..1023
      int jp = task & 31;         // j-pair index
      int cc = task >> 5;         // c-chunk 0..31 (8 dv each)
      int j = jp * 2;
      int c = cc * 8;             // local col base
      int gcol = n0 + c;
      int w = gcol >> 5, dv = gcol & 31;
      const ushort* vp =
          &vlin[(size_t)(b * 4096 + j * 64 + w) * 256 + hd * 32 + dv];
      u8v v0 = *(const u8v*)vp;
      u8v v1 = *(const u8v*)(vp + 64 * 256);  // next j
#pragma unroll
      for (int q = 0; q < 8; q++) {
        ushort pr[2] = {(ushort)v0[q], (ushort)v1[q]};
        *(uint*)&Bt[(c + q) * 68 + j] = *(uint*)pr;
      }
    }
  }
  __syncthreads();

  int tm = lane & 15, quad = lane >> 4;
  int wn = wave * 64;
  f4v acc[4][4] = {};
#pragma unroll
  for (int kc = 0; kc < 64; kc += 32) {
    s8v ah_[4], al_[4], bb[4];
#pragma unroll
    for (int mi = 0; mi < 4; mi++) {
      int idx = (mi * 16 + tm) * 68 + kc + quad * 8;
      union { s8v v; unsigned long long u[2]; } th, tl;
      th.u[0] = *(const unsigned long long*)&Ah[idx];
      th.u[1] = *(const unsigned long long*)&Ah[idx + 4];
      tl.u[0] = *(const unsigned long long*)&Al[idx];
      tl.u[1] = *(const unsigned long long*)&Al[idx + 4];
      ah_[mi] = th.v;
      al_[mi] = tl.v;
    }
#pragma unroll
    for (int ni = 0; ni < 4; ni++) {
      int idx = (wn + ni * 16 + tm) * 68 + kc + quad * 8;
      union { s8v v; unsigned long long u[2]; } tb;
      tb.u[0] = *(const unsigned long long*)&Bt[idx];
      tb.u[1] = *(const unsigned long long*)&Bt[idx + 4];
      bb[ni] = tb.v;
    }
#pragma unroll
    for (int mi = 0; mi < 4; mi++)
#pragma unroll
      for (int ni = 0; ni < 4; ni++) {
        acc[mi][ni] = __builtin_amdgcn_mfma_f32_16x16x32_bf16(
            ah_[mi], bb[ni], acc[mi][ni], 0, 0, 0);
        acc[mi][ni] = __builtin_amdgcn_mfma_f32_16x16x32_bf16(
            al_[mi], bb[ni], acc[mi][ni], 0, 0, 0);
      }
  }

  ushort* rp = r1 + (size_t)(b * 8 + hd) * 64 * 2048;
#pragma unroll
  for (int mi = 0; mi < 4; mi++) {
#pragma unroll
    for (int ni = 0; ni < 4; ni++) {
      int col = n0 + wn + ni * 16 + tm;
#pragma unroll
      for (int r = 0; r < 4; r++) {
        int row = mi * 16 + quad * 4 + r;
        rp[(size_t)row * 2048 + col] = f2bf(acc[mi][ni][r]);
      }
    }
  }
}

// ---------------------------------------------------------------------------
// K5b (MFMA): yT[(b*4096+h*64+w')][hd*32+dv]
//               = sum_w r1[b,hd,h,w*32+dv] * attnw[w][w']
// ---------------------------------------------------------------------------
__global__ __launch_bounds__(256) void k_rw(const ushort* __restrict__ r1,
                                            const float* __restrict__ attnw,
                                            ushort* __restrict__ yT) {
  __shared__ __align__(16) ushort As[8 * 2180];   // 34880 B
  __shared__ __align__(16) ushort Wh[64 * 68];    //  8704 B  (hi)
  __shared__ __align__(16) ushort Wl[64 * 68];    //  8704 B  (lo)

  int bx = blockIdx.x;
  int ht = bx & 7, hd = (bx >> 3) & 7, b = bx >> 6;
  int tid = threadIdx.x;
  int lane = tid & 63, wave = tid >> 6;

  {
    int h = tid >> 5;                // 0..7
    int t = tid & 31;
    const ushort* rp =
        r1 + (size_t)((b * 8 + hd) * 64 + ht * 8 + h) * 2048;
#pragma unroll
    for (int i = 0; i < 4; i++) {
      int chunk = t + 32 * i;        // 0..127
      int w = (chunk >> 2) * 2;      // even w
      int dv0 = (chunk & 3) * 8;
      u8v v0 = *(const u8v*)&rp[w * 32 + dv0];
      u8v v1 = *(const u8v*)&rp[(w + 1) * 32 + dv0];
#pragma unroll
      for (int j = 0; j < 8; j++) {
        ushort pr[2] = {(ushort)v0[j], (ushort)v1[j]};
        *(uint*)&As[h * 2180 + (dv0 + j) * 68 + w] = *(uint*)pr;
      }
    }
  }
  {
    const float* ap = attnw + (size_t)(b * 8 + hd) * 4096;
#pragma unroll
    for (int p = 0; p < 4; p++) {
      int w = (tid >> 4) + p * 16;
      int wq = (tid & 15) * 4;
      float4 v = *(const float4*)&ap[w * 64 + wq];
      float f_[4] = {v.x, v.y, v.z, v.w};
#pragma unroll
      for (int j = 0; j < 4; j++) {
        ushort hi = f2bf(f_[j]);
        Wh[(wq + j) * 68 + w] = hi;
        Wl[(wq + j) * 68 + w] = f2bf(f_[j] - bf2f(hi));
      }
    }
  }
  __syncthreads();

  int tm = lane & 15, quad = lane >> 4;
  int h0 = wave * 2;
  f4v acc[4][4] = {};
#pragma unroll
  for (int kc = 0; kc < 64; kc += 32) {
    s8v a[4], bh[4], bl[4];
#pragma unroll
    for (int mi = 0; mi < 4; mi++) {
      int h = h0 + (mi >> 1);
      int dv = (mi & 1) * 16 + tm;
      int idx = h * 2180 + dv * 68 + kc + quad * 8;
      union { s8v v; unsigned long long u[2]; } t_;
      t_.u[0] = *(const unsigned long long*)&As[idx];
      t_.u[1] = *(const unsigned long long*)&As[idx + 4];
      a[mi] = t_.v;
    }
#pragma unroll
    for (int ni = 0; ni < 4; ni++) {
      int idx = (ni * 16 + tm) * 68 + kc + quad * 8;
      union { s8v v; unsigned long long u[2]; } th, tl;
      th.u[0] = *(const unsigned long long*)&Wh[idx];
      th.u[1] = *(const unsigned long long*)&Wh[idx + 4];
      tl.u[0] = *(const unsigned long long*)&Wl[idx];
      tl.u[1] = *(const unsigned long long*)&Wl[idx + 4];
      bh[ni] = th.v;
      bl[ni] = tl.v;
    }
#pragma unroll
    for (int mi = 0; mi < 4; mi++)
#pragma unroll
      for (int ni = 0; ni < 4; ni++) {
        acc[mi][ni] = __builtin_amdgcn_mfma_f32_16x16x32_bf16(
            a[mi], bh[ni], acc[mi][ni], 0, 0, 0);
        acc[mi][ni] = __builtin_amdgcn_mfma_f32_16x16x32_bf16(
            a[mi], bl[ni], acc[mi][ni], 0, 0, 0);
      }
  }

#pragma unroll
  for (int mi = 0; mi < 4; mi++) {
    int h = ht * 8 + h0 + (mi >> 1);
    int dv0 = (mi & 1) * 16 + quad * 4;
#pragma unroll
    for (int ni = 0; ni < 4; ni++) {
      int wp = ni * 16 + tm;
      ushort pk[4];
#pragma unroll
      for (int r = 0; r < 4; r++) pk[r] = f2bf(acc[mi][ni][r]);
      *(uint2*)&yT[(size_t)(b * 4096 + h * 64 + wp) * 256 + hd * 32 + dv0] =
          *(uint2*)pk;
    }
  }
}

// ---------------------------------------------------------------------------
// K_out: final GEMM, 128m x 256n, 8 waves (512 thr): full-N reuse (A read
// once) WITHOUT the acc[4][8] VGPR blowup -- each wave owns a 64x64 quadrant
// (acc[4][4], ~110 VGPR vs 180). Same wave count as a (512,2) grid.
// ---------------------------------------------------------------------------
__global__ __launch_bounds__(512) void k_out(const ushort* __restrict__ A,
                                             const ushort* __restrict__ W,
                                             const float* __restrict__ bias,
                                             float* __restrict__ out) {
  __shared__ __align__(16) ushort As[128 * 32];
  __shared__ __align__(16) ushort Bs[256 * 32];

  int m0 = blockIdx.x * 128;
  int tid = threadIdx.x;
  int lane = tid & 63, wave = tid >> 6;      // 8 waves
  int wm = (wave & 1) * 64, wn = (wave >> 1) * 64;
  int tm = lane & 15, quad = lane >> 4;
  int xorv = (tm ^ (tm >> 2)) & 3;
  int srow = lane >> 2;
  int slot = lane & 3;

  const ushort* Abase = A + (size_t)m0 * 256;

  f4v acc[4][4] = {};

  for (int kc = 0; kc < 256; kc += 32) {
    __syncthreads();
    // As: 128 rows, 1 gload16 per wave
    {
      int rb = wave * 16;
      int row = rb + srow;
      int xr = (row ^ (row >> 2)) & 3;
      gload16(&Abase[(size_t)row * 256 + kc + (slot ^ xr) * 8], &As[rb * 32]);
    }
    // Bs: 256 rows, 2 gload16 per wave
#pragma unroll
    for (int it = 0; it < 2; it++) {
      int rb = wave * 16 + it * 128;
      int row = rb + srow;
      int xr = (row ^ (row >> 2)) & 3;
      gload16(&W[(size_t)row * 256 + kc + (slot ^ xr) * 8], &Bs[rb * 32]);
    }
    __syncthreads();

    s8v a[4], bfr[4];
#pragma unroll
    for (int mi = 0; mi < 4; mi++)
      a[mi] = *(const s8v*)&As[(wm + mi * 16 + tm) * 32 + (quad ^ xorv) * 8];
#pragma unroll
    for (int ni = 0; ni < 4; ni++)
      bfr[ni] = *(const s8v*)&Bs[(wn + ni * 16 + tm) * 32 + (quad ^ xorv) * 8];
#pragma unroll
    for (int mi = 0; mi < 4; mi++)
#pragma unroll
      for (int ni = 0; ni < 4; ni++)
        acc[mi][ni] = __builtin_amdgcn_mfma_f32_16x16x32_bf16(
            a[mi], bfr[ni], acc[mi][ni], 0, 0, 0);
  }

  // C/D layout: col = lane&15, row = quad*4 + reg
#pragma unroll
  for (int mi = 0; mi < 4; mi++) {
#pragma unroll
    for (int ni = 0; ni < 4; ni++) {
      int col = wn + ni * 16 + tm;
      float bv = bias[col];
#pragma unroll
      for (int r = 0; r < 4; r++) {
        int row = m0 + wm + mi * 16 + quad * 4 + r;
        out[(size_t)row * 256 + col] = acc[mi][ni][r] + bv;
      }
    }
  }
}

// ---------------------------------------------------------------------------
extern "C" void kernel_launch(void* const* d_in, const int* in_sizes, int n_in,
                              void* d_out, int out_size, void* d_ws,
                              size_t ws_size, hipStream_t stream) {
  const float* x      = (const float*)d_in[0];
  const float* dwqh_w = (const float*)d_in[1];
  const float* dwqh_b = (const float*)d_in[2];
  const float* fcqh_w = (const float*)d_in[3];
  const float* fcqh_b = (const float*)d_in[4];
  const float* dwkh_w = (const float*)d_in[5];
  const float* dwkh_b = (const float*)d_in[6];
  const float* fckh_w = (const float*)d_in[7];
  const float* fckh_b = (const float*)d_in[8];
  const float* Bh     = (const float*)d_in[9];
  const float* dwv_w  = (const float*)d_in[10];
  const float* dwv_b  = (const float*)d_in[11];
  const float* fcv_w  = (const float*)d_in[12];
  const float* fcv_b  = (const float*)d_in[13];
  const float* dwqw_w = (const float*)d_in[14];
  const float* dwqw_b = (const float*)d_in[15];
  const float* fcqw_w = (const float*)d_in[16];
  const float* fcqw_b = (const float*)d_in[17];
  const float* dwkw_w = (const float*)d_in[18];
  const float* dwkw_b = (const float*)d_in[19];
  const float* fckw_w = (const float*)d_in[20];
  const float* fckw_b = (const float*)d_in[21];
  const float* Bw     = (const float*)d_in[22];
  const float* fco_w  = (const float*)d_in[23];
  const float* fco_b  = (const float*)d_in[24];

  char* base = (char*)d_ws;
  ushort* P1 = (ushort*)(base);                  // convV, later r1
  ushort* P2 = (ushort*)(base + 33554432);       // yT
  ushort* P3 = (ushort*)(base + 67108864);       // vlin
  ushort* whl  = (ushort*)(base + 100663296);    // 4 x (hi|lo) 65536 bf16
  ushort* wv_bf = (ushort*)(base + 101711872);   // 2 x 65536 bf16
  float* qhm = (float*)(base + 101974016);
  float* khm = qhm + 262144;
  float* qwm = khm + 262144;
  float* kwm = qwm + 262144;
  float* qhl = kwm + 262144;
  float* khl = qhl + 262144;
  float* qwl = khl + 262144;
  float* kwl = qwl + 262144;
  float* ah  = kwl + 262144;                     // 524288
  float* awt = ah + 524288;                      // 524288
  if (ws_size < 115000000ull) return;

  const float scale = 0.17677669529663687f;  // 32^-0.5

  k_conv<<<5632, 256, 0, stream>>>(x, dwqh_w, dwqh_b, dwkh_w, dwkh_b, dwv_w,
                                   dwv_b, dwqw_w, dwqw_b, dwkw_w, dwkw_b,
                                   fcqh_w, fckh_w, fcqw_w, fckw_w, fcv_w,
                                   fco_w, whl, wv_bf, P1,
                                   qhm, khm, qwm, kwm);
  k_mmv<<<1280, 256, 0, stream>>>(P1, wv_bf, fcv_b, P3,
                                  qhm, khm, qwm, kwm, whl, fcqh_b, fckh_b,
                                  fcqw_b, fckw_b, qhl, khl, qwl, kwl);
  k_attn<<<256, 256, 0, stream>>>(qhl, khl, Bh, ah, qwl, kwl, Bw, awt, scale);
  k_av<<<1024, 256, 0, stream>>>(ah, P3, P1);
  k_rw<<<1024, 256, 0, stream>>>(P1, awt, P2);
  k_out<<<512, 512, 0, stream>>>(P2, wv_bf + 65536, fco_b, (float*)d_out);
}

// Round 12
// 262.310 us; speedup vs baseline: 1.1509x; 1.0193x over previous
//
#include <hip/hip_runtime.h>
#include <hip/hip_bf16.h>

typedef float f4v __attribute__((ext_vector_type(4)));
typedef short s8v __attribute__((ext_vector_type(8)));
typedef unsigned short u8v __attribute__((ext_vector_type(8)));

__device__ __forceinline__ float bf2f(ushort u) {
  union { unsigned int i; float f; } c; c.i = ((unsigned int)u) << 16;
  return c.f;
}
__device__ __forceinline__ ushort f2bf(float f) {
  union { ushort s; __hip_bfloat16 h; } c; c.h = __float2bfloat16(f);
  return c.s;
}
// Direct global->LDS 16B DMA. lds base must be wave-uniform; lane l writes
// lds + l*16. Source address is per-lane.
__device__ __forceinline__ void gload16(const ushort* g, ushort* l) {
  __builtin_amdgcn_global_load_lds(
      (const __attribute__((address_space(1))) unsigned int*)g,
      (__attribute__((address_space(3))) unsigned int*)l, 16, 0, 0);
}

// ---------------------------------------------------------------------------
// K1 (+prep fold): bx<4096: per (b,c) conv plane work.
// bx in [4096,5120): cast four fp32 q/k weights [o][k] to bf16 hi/lo pairs.
// bx in [5120,5632): cast fc_v|fc_o to bf16 [n][k].
// ---------------------------------------------------------------------------
__global__ __launch_bounds__(256) void k_conv(
    const float* __restrict__ x,
    const float* __restrict__ wqh, const float* __restrict__ bqh,
    const float* __restrict__ wkh, const float* __restrict__ bkh,
    const float* __restrict__ wv,  const float* __restrict__ bv,
    const float* __restrict__ wqw, const float* __restrict__ bqw,
    const float* __restrict__ wkw, const float* __restrict__ bkw,
    const float* __restrict__ fq0, const float* __restrict__ fq1,
    const float* __restrict__ fq2, const float* __restrict__ fq3,
    const float* __restrict__ fwv, const float* __restrict__ fwo,
    ushort* __restrict__ whl, ushort* __restrict__ wbf,
    ushort* __restrict__ convV,
    float* __restrict__ qhm, float* __restrict__ khm,
    float* __restrict__ qwm, float* __restrict__ kwm) {
  __shared__ float xs[68 * 68];
  __shared__ float wl[5][9];
  __shared__ float bl[5];

  int bx = blockIdx.x;
  int tid = threadIdx.x;

  if (bx >= 4096) {
    int pb = bx - 4096;
    if (pb < 1024) {
      int mat = pb >> 8;
      int i = (pb & 255) * 256 + tid;
      const float* p = mat == 0 ? fq0 : mat == 1 ? fq1 : mat == 2 ? fq2 : fq3;
      float f = p[i];
      ushort hi = f2bf(f);
      ushort lo = f2bf(f - bf2f(hi));
      whl[(size_t)mat * 131072 + i] = hi;
      whl[(size_t)mat * 131072 + 65536 + i] = lo;
    } else {
      int idx = (pb - 1024) * 256 + tid;  // 0..131071
      const float* src = (idx >> 16) ? fwo : fwv;
      wbf[idx] = f2bf(src[idx & 65535]);
    }
    return;
  }

  int b = bx >> 8;
  int c = bx & 255;
  int lane = tid & 63, wave = tid >> 6;

  const float* xp = x + (size_t)(b * 256 + c) * 4096;
#pragma unroll
  for (int i = 0; i < 4; i++) {
    int flat = tid + i * 256;          // 0..1023
    int r = flat >> 4, c4 = (flat & 15) * 4;
    float4 v = *(const float4*)(xp + r * 64 + c4);
    *(float4*)&xs[(r + 1) * 68 + 4 + c4] = v;
  }
  if (tid < 72) { xs[tid] = 0.f; xs[65 * 68 + tid] = 0.f; }
  if (tid >= 72 && tid < 200) {
    int t = tid - 72;
    int pr = (t & 63) + 1, side = t >> 6;
    xs[pr * 68 + (side ? 68 : 3)] = 0.f;
  }
  if (tid >= 200 && tid < 245) {
    int t = tid - 200;
    int cw = t / 9, wi = t % 9;
    const float* wp = cw == 0 ? wqh : cw == 1 ? wkh : cw == 2 ? wv
                    : cw == 3 ? wqw : wkw;
    wl[cw][wi] = wp[c * 9 + wi];
  } else if (tid >= 245 && tid < 250) {
    int cw = tid - 245;
    const float* bp = cw == 0 ? bqh : cw == 1 ? bkh : cw == 2 ? bv
                    : cw == 3 ? bqw : bkw;
    bl[cw] = bp[c];
  }
  __syncthreads();

  // ---- v-conv: wave handles rows h0..h0+15, lane = output col ----
  {
    int w = lane;
    int h0 = wave * 16;
    float v0 = wl[2][0], v1 = wl[2][1], v2 = wl[2][2];
    float v3 = wl[2][3], v4 = wl[2][4], v5 = wl[2][5];
    float v6 = wl[2][6], v7 = wl[2][7], v8 = wl[2][8];
    float bvv = bl[2];
    float a00 = xs[h0 * 68 + 3 + w], a01 = xs[h0 * 68 + 4 + w],
          a02 = xs[h0 * 68 + 5 + w];
    float a10 = xs[(h0 + 1) * 68 + 3 + w], a11 = xs[(h0 + 1) * 68 + 4 + w],
          a12 = xs[(h0 + 1) * 68 + 5 + w];
    ushort* cp = convV + (size_t)(b * 256 + c) * 4096 + h0 * 64 + w;
#pragma unroll
    for (int i = 0; i < 16; i++) {
      int pr = h0 + i + 2;
      float a20 = xs[pr * 68 + 3 + w];
      float a21 = xs[pr * 68 + 4 + w];
      float a22 = xs[pr * 68 + 5 + w];
      float acc = bvv;
      acc += a00 * v0 + a01 * v1 + a02 * v2;
      acc += a10 * v3 + a11 * v4 + a12 * v5;
      acc += a20 * v6 + a21 * v7 + a22 * v8;
      cp[i * 64] = f2bf(acc);
      a00 = a10; a01 = a11; a02 = a12;
      a10 = a20; a11 = a21; a12 = a22;
    }
  }

  // ---- pooled means from linearity: wave0 rows, wave1 cols ----
  if (wave == 0) {
    float rs = 0.f, e0 = 0.f, e1 = 0.f;
    const float* rowp = &xs[(lane + 1) * 68 + 4];
#pragma unroll
    for (int i = 0; i < 16; i++) {
      float4 v = *(const float4*)(rowp + i * 4);
      rs += (v.x + v.y) + (v.z + v.w);
      if (i == 0) e0 = v.x;
      if (i == 15) e1 = v.w;
    }
    float rsP = __shfl(rs, lane - 1, 64); rsP = (lane == 0) ? 0.f : rsP;
    float rsN = __shfl(rs, lane + 1, 64); rsN = (lane == 63) ? 0.f : rsN;
    float e0P = __shfl(e0, lane - 1, 64); e0P = (lane == 0) ? 0.f : e0P;
    float e0N = __shfl(e0, lane + 1, 64); e0N = (lane == 63) ? 0.f : e0N;
    float e1P = __shfl(e1, lane - 1, 64); e1P = (lane == 0) ? 0.f : e1P;
    float e1N = __shfl(e1, lane + 1, 64); e1N = (lane == 63) ? 0.f : e1N;
    float RS[3] = {rsP, rs, rsN};
    float E0[3] = {e0P, e0, e0N};
    float E1[3] = {e1P, e1, e1N};
    float vq = 0.f, vk = 0.f;
#pragma unroll
    for (int ky = 0; ky < 3; ky++) {
      vq += (wl[0][ky * 3] + wl[0][ky * 3 + 1] + wl[0][ky * 3 + 2]) * RS[ky]
            - wl[0][ky * 3] * E1[ky] - wl[0][ky * 3 + 2] * E0[ky];
      vk += (wl[1][ky * 3] + wl[1][ky * 3 + 1] + wl[1][ky * 3 + 2]) * RS[ky]
            - wl[1][ky * 3] * E1[ky] - wl[1][ky * 3 + 2] * E0[ky];
    }
    qhm[(size_t)(b * 256 + c) * 64 + lane] = vq * (1.f / 64.f) + bl[0];
    khm[(size_t)(b * 256 + c) * 64 + lane] = vk * (1.f / 64.f) + bl[1];
  } else if (wave == 1) {
    float cs = 0.f, f0 = 0.f, f1 = 0.f;
#pragma unroll
    for (int r = 0; r < 64; r++) {
      float v = xs[(r + 1) * 68 + 4 + lane];
      cs += v;
      if (r == 0) f0 = v;
      if (r == 63) f1 = v;
    }
    float csP = __shfl(cs, lane - 1, 64); csP = (lane == 0) ? 0.f : csP;
    float csN = __shfl(cs, lane + 1, 64); csN = (lane == 63) ? 0.f : csN;
    float f0P = __shfl(f0, lane - 1, 64); f0P = (lane == 0) ? 0.f : f0P;
    float f0N = __shfl(f0, lane + 1, 64); f0N = (lane == 63) ? 0.f : f0N;
    float f1P = __shfl(f1, lane - 1, 64); f1P = (lane == 0) ? 0.f : f1P;
    float f1N = __shfl(f1, lane + 1, 64); f1N = (lane == 63) ? 0.f : f1N;
    float CS[3] = {csP, cs, csN};
    float F0[3] = {f0P, f0, f0N};
    float F1[3] = {f1P, f1, f1N};
    float vq = 0.f, vk = 0.f;
#pragma unroll
    for (int kx = 0; kx < 3; kx++) {
      vq += (wl[3][kx] + wl[3][3 + kx] + wl[3][6 + kx]) * CS[kx]
            - wl[3][kx] * F1[kx] - wl[3][6 + kx] * F0[kx];
      vk += (wl[4][kx] + wl[4][3 + kx] + wl[4][6 + kx]) * CS[kx]
            - wl[4][kx] * F1[kx] - wl[4][6 + kx] * F0[kx];
    }
    qwm[(size_t)(b * 256 + c) * 64 + lane] = vq * (1.f / 64.f) + bl[3];
    kwm[(size_t)(b * 256 + c) * 64 + lane] = vk * (1.f / 64.f) + bl[4];
  }
}

// ---------------------------------------------------------------------------
// K2v (fused launch): bx<1024: vlin GEMM, 128m x 128n tile (acc[4][4], low
// VGPR), A transposed from convV [b][k=256][m=4096], B via global_load_lds.
// bx in [1024,1280): pooled q/k linear GEMM, K-chunks of 32 (18.4KB union).
// ---------------------------------------------------------------------------
__global__ __launch_bounds__(256) void k_mmv(
    const ushort* __restrict__ A, const ushort* __restrict__ W,
    const float* __restrict__ bias, ushort* __restrict__ out,
    const float* __restrict__ s0, const float* __restrict__ s1,
    const float* __restrict__ s2, const float* __restrict__ s3,
    const ushort* __restrict__ whl,
    const float* __restrict__ b0, const float* __restrict__ b1,
    const float* __restrict__ b2, const float* __restrict__ b3,
    float* __restrict__ d0, float* __restrict__ d1,
    float* __restrict__ d2, float* __restrict__ d3) {
  __shared__ __align__(16) ushort pool[9216];   // 18432 B union

  int bx = blockIdx.x;
  int tid = threadIdx.x;
  int lane = tid & 63, wave = tid >> 6;
  int tm = lane & 15, quad = lane >> 4;

  if (bx < 1024) {
    // ---------------- vlin GEMM path (128x128) ----------------
    ushort* As = pool;           // 128 rows x 32 k (64B rows)
    ushort* Bs = pool + 4096;    // 128 rows x 32 k

    int m0 = (bx >> 1) * 128;
    int n0 = (bx & 1) * 128;
    int wm = (wave & 1) * 64, wn = (wave >> 1) * 64;
    int xorv = (tm ^ (tm >> 2)) & 3;
    int srow = lane >> 2;
    int slot = lane & 3;

    const ushort* Abase = A + (size_t)(m0 >> 12) * (256 * 4096) + (m0 & 4095);

    f4v acc[4][4] = {};

    for (int kc = 0; kc < 256; kc += 32) {
      __syncthreads();
      // As: LDS transpose (register path), XOR slot layout
      {
        int kr2 = (tid & 15) * 2, mg = tid >> 4;
        u8v v0 = *(const u8v*)&Abase[(size_t)(kc + kr2) * 4096 + mg * 8];
        u8v v1 = *(const u8v*)&Abase[(size_t)(kc + kr2 + 1) * 4096 + mg * 8];
        int sl0 = kr2 >> 3, k7 = kr2 & 7;
#pragma unroll
        for (int j = 0; j < 8; j++) {
          int row = mg * 8 + j;
          int xr = (row ^ (row >> 2)) & 3;
          ushort pr[2] = {v0[j], v1[j]};
          *(uint*)&As[row * 32 + (sl0 ^ xr) * 8 + k7] = *(uint*)pr;
        }
      }
      // Bs: 128 rows via direct-to-LDS DMA (2 per wave)
#pragma unroll
      for (int it = 0; it < 2; it++) {
        int rb = wave * 16 + it * 64;
        int row = rb + srow;
        int xr = (row ^ (row >> 2)) & 3;
        gload16(&W[(size_t)(n0 + row) * 256 + kc + (slot ^ xr) * 8],
                &Bs[rb * 32]);
      }
      __syncthreads();

      s8v a[4], bfr[4];
#pragma unroll
      for (int mi = 0; mi < 4; mi++)
        a[mi] = *(const s8v*)&As[(wm + mi * 16 + tm) * 32 + (quad ^ xorv) * 8];
#pragma unroll
      for (int ni = 0; ni < 4; ni++)
        bfr[ni] =
            *(const s8v*)&Bs[(wn + ni * 16 + tm) * 32 + (quad ^ xorv) * 8];
#pragma unroll
      for (int mi = 0; mi < 4; mi++)
#pragma unroll
        for (int ni = 0; ni < 4; ni++)
          acc[mi][ni] = __builtin_amdgcn_mfma_f32_16x16x32_bf16(
              a[mi], bfr[ni], acc[mi][ni], 0, 0, 0);
    }

    // C/D layout: col = lane&15, row = quad*4 + reg
#pragma unroll
    for (int mi = 0; mi < 4; mi++) {
#pragma unroll
      for (int ni = 0; ni < 4; ni++) {
        int col = n0 + wn + ni * 16 + tm;
        float bv = bias[col];
#pragma unroll
        for (int r = 0; r < 4; r++) {
          int row = m0 + wm + mi * 16 + quad * 4 + r;
          out[(size_t)row * 256 + col] = f2bf(acc[mi][ni][r] + bv);
        }
      }
    }
    return;
  }

  // ---------------- pooled q/k linear path (K-chunk 32) ----------------
  {
    int t = bx - 1024;            // 0..255
    int z = t & 3;
    int n0 = ((t >> 2) & 3) * 64;
    int b = t >> 4;

    ushort* Ah = pool;            // 64 x 36
    ushort* Al = pool + 2304;
    ushort* Wh = pool + 4608;
    ushort* Wl = pool + 6912;

    const float* At = z == 0 ? s0 : z == 1 ? s1 : z == 2 ? s2 : s3;
    const ushort* Whp = whl + (size_t)z * 131072;
    const ushort* Wlp = Whp + 65536;
    const float* biasz = z == 0 ? b0 : z == 1 ? b1 : z == 2 ? b2 : b3;
    float* Cout = z == 0 ? d0 : z == 1 ? d1 : z == 2 ? d2 : d3;

    const float* Ab = At + (size_t)b * 256 * 64;  // [k][m], m contiguous

    int wm = (wave & 1) * 32, wn = (wave >> 1) * 32;

    f4v acc[2][2] = {};

    for (int kc = 0; kc < 256; kc += 32) {
      __syncthreads();
      // stage A: 64m x 32k fp32 -> hi/lo transpose (one pass, 256 threads)
      {
        int mq = tid & 15, kp = tid >> 4;  // kp 0..15
        int k0 = kp * 2, m0 = mq * 4;
        float4 v0 = *(const float4*)&Ab[(size_t)(kc + k0) * 64 + m0];
        float4 v1 = *(const float4*)&Ab[(size_t)(kc + k0 + 1) * 64 + m0];
        float f0[4] = {v0.x, v0.y, v0.z, v0.w};
        float f1[4] = {v1.x, v1.y, v1.z, v1.w};
#pragma unroll
        for (int j = 0; j < 4; j++) {
          ushort h0 = f2bf(f0[j]), h1 = f2bf(f1[j]);
          ushort l0 = f2bf(f0[j] - bf2f(h0)), l1 = f2bf(f1[j] - bf2f(h1));
          ushort ph[2] = {h0, h1};
          ushort pl[2] = {l0, l1};
          *(uint*)&Ah[(m0 + j) * 36 + k0] = *(uint*)ph;
          *(uint*)&Al[(m0 + j) * 36 + k0] = *(uint*)pl;
        }
      }
      // stage W: 64n x 32k hi and lo (8B stores; 72B row stride is 8B-aligned)
      {
        int nr = tid >> 2, k8 = (tid & 3) * 8;
        u8v vh = *(const u8v*)&Whp[(size_t)(n0 + nr) * 256 + kc + k8];
        u8v vl = *(const u8v*)&Wlp[(size_t)(n0 + nr) * 256 + kc + k8];
        union { u8v v; unsigned long long u[2]; } ch, cl;
        ch.v = vh; cl.v = vl;
        *(unsigned long long*)&Wh[nr * 36 + k8] = ch.u[0];
        *(unsigned long long*)&Wh[nr * 36 + k8 + 4] = ch.u[1];
        *(unsigned long long*)&Wl[nr * 36 + k8] = cl.u[0];
        *(unsigned long long*)&Wl[nr * 36 + k8 + 4] = cl.u[1];
      }
      __syncthreads();

      s8v ah[2], al[2], bh[2], bl[2];
#pragma unroll
      for (int mi = 0; mi < 2; mi++) {
        int idx = (wm + mi * 16 + tm) * 36 + quad * 8;
        union { s8v v; unsigned long long u[2]; } th, tl;
        th.u[0] = *(const unsigned long long*)&Ah[idx];
        th.u[1] = *(const unsigned long long*)&Ah[idx + 4];
        tl.u[0] = *(const unsigned long long*)&Al[idx];
        tl.u[1] = *(const unsigned long long*)&Al[idx + 4];
        ah[mi] = th.v;
        al[mi] = tl.v;
      }
#pragma unroll
      for (int ni = 0; ni < 2; ni++) {
        int idx = (wn + ni * 16 + tm) * 36 + quad * 8;
        union { s8v v; unsigned long long u[2]; } th, tl;
        th.u[0] = *(const unsigned long long*)&Wh[idx];
        th.u[1] = *(const unsigned long long*)&Wh[idx + 4];
        tl.u[0] = *(const unsigned long long*)&Wl[idx];
        tl.u[1] = *(const unsigned long long*)&Wl[idx + 4];
        bh[ni] = th.v;
        bl[ni] = tl.v;
      }
#pragma unroll
      for (int mi = 0; mi < 2; mi++)
#pragma unroll
        for (int ni = 0; ni < 2; ni++) {
          acc[mi][ni] = __builtin_amdgcn_mfma_f32_16x16x32_bf16(
              ah[mi], bh[ni], acc[mi][ni], 0, 0, 0);
          acc[mi][ni] = __builtin_amdgcn_mfma_f32_16x16x32_bf16(
              ah[mi], bl[ni], acc[mi][ni], 0, 0, 0);
          acc[mi][ni] = __builtin_amdgcn_mfma_f32_16x16x32_bf16(
              al[mi], bh[ni], acc[mi][ni], 0, 0, 0);
        }
    }

#pragma unroll
    for (int mi = 0; mi < 2; mi++) {
#pragma unroll
      for (int ni = 0; ni < 2; ni++) {
        int n = n0 + wn + ni * 16 + tm;
        float bv = biasz[n];
#pragma unroll
        for (int r = 0; r < 4; r++) {
          int m = b * 64 + wm + mi * 16 + quad * 4 + r;
          Cout[(size_t)m * 256 + n] = acc[mi][ni][r] + bv;
        }
      }
    }
  }
}

// ---------------------------------------------------------------------------
// K3: attention softmax, both axes fused. Block = (set,b,hd): stages q/k
// once, loops all 16 row-quads. High occupancy; attn stays L2/L3-resident
// for consumers (in-block recompute fusion measured WORSE in round 6).
// ---------------------------------------------------------------------------
__global__ __launch_bounds__(256) void k_attn(
    const float* __restrict__ qh, const float* __restrict__ kh,
    const float* __restrict__ Bh, float* __restrict__ ah,
    const float* __restrict__ qw, const float* __restrict__ kw,
    const float* __restrict__ Bw, float* __restrict__ aw, float scale) {
  __shared__ float qs[64 * 33];
  __shared__ float ks[64 * 33];

  int bx = blockIdx.x;             // 256 blocks
  int setw = bx >> 7;
  int rem = bx & 127;
  int hd = rem & 7, b = rem >> 3;
  int tid = threadIdx.x;
  int wave = tid >> 6, lane = tid & 63;

  const float* q = setw ? qw : qh;
  const float* k = setw ? kw : kh;
  const float* Bb = setw ? Bw : Bh;
  float* attn = setw ? aw : ah;

#pragma unroll
  for (int it = 0; it < 8; it++) {
    int f = tid + it * 256;
    int j = f >> 5, d = f & 31;
    size_t src = (size_t)(b * 64 + j) * 256 + hd * 32 + d;
    qs[j * 33 + d] = q[src];
    ks[j * 33 + d] = k[src];
  }
  __syncthreads();

  const float* Bp = Bb + (size_t)(hd * 64) * 64;
  float* ap = attn + (size_t)((b * 8 + hd) * 64) * 64;
  int j = lane;
  for (int ig = 0; ig < 16; ig++) {
    int i = ig * 4 + wave;
    float dot = 0.f;
#pragma unroll
    for (int d = 0; d < 32; d++) dot += qs[i * 33 + d] * ks[j * 33 + d];
    float logit = dot * scale + Bp[i * 64 + j];
    float mx = logit;
#pragma unroll
    for (int off = 32; off > 0; off >>= 1)
      mx = fmaxf(mx, __shfl_xor(mx, off, 64));
    float e = __expf(logit - mx);
    float sum = e;
#pragma unroll
    for (int off = 32; off > 0; off >>= 1) sum += __shfl_xor(sum, off, 64);
    ap[i * 64 + j] = e / sum;
  }
}

// ---------------------------------------------------------------------------
// K5a (MFMA): r1[b][hd][h=64][c=2048] = attn_h[64x64] @ vlinT[64][2048]
// Bt is K-SPLIT: only 32 of 64 j staged at a time ([256][36], 18.4KB) ->
// total LDS 35.8KB (was 52.2) -> 4 blocks/CU (was 3).
// ---------------------------------------------------------------------------
__global__ __launch_bounds__(256) void k_av(const float* __restrict__ attn,
                                            const ushort* __restrict__ vlin,
                                            ushort* __restrict__ r1) {
  __shared__ __align__(16) ushort Ah[64 * 68];   // attn hi  [i][j]  (full j)
  __shared__ __align__(16) ushort Al[64 * 68];   // attn lo  [i][j]  (full j)
  __shared__ __align__(16) ushort Bt[256 * 36];  // vlin^T [c][j-half]

  int bx = blockIdx.x;
  int nt = bx & 7, hd = (bx >> 3) & 7, b = bx >> 6;
  int n0 = nt * 256;
  int tid = threadIdx.x;
  int lane = tid & 63, wave = tid >> 6;
  int tm = lane & 15, quad = lane >> 4;
  int wn = wave * 64;

  // ---- stage attn -> hi/lo bf16, [i][j] (j contiguous, full width) ----
  const float* ap = attn + (size_t)(b * 8 + hd) * 4096;
  {
    int i = tid >> 2;          // row 0..63
    int j0 = (tid & 3) * 16;   // 16 cols per thread
#pragma unroll
    for (int p = 0; p < 4; p++) {
      float4 v = *(const float4*)&ap[i * 64 + j0 + p * 4];
      float f_[4] = {v.x, v.y, v.z, v.w};
      ushort ph[4], pl[4];
#pragma unroll
      for (int q = 0; q < 4; q++) {
        ph[q] = f2bf(f_[q]);
        pl[q] = f2bf(f_[q] - bf2f(ph[q]));
      }
      *(uint2*)&Ah[i * 68 + j0 + p * 4] = *(uint2*)ph;
      *(uint2*)&Al[i * 68 + j0 + p * 4] = *(uint2*)pl;
    }
  }

  f4v acc[4][4] = {};
#pragma unroll
  for (int kc = 0; kc < 64; kc += 32) {
    if (kc) __syncthreads();   // prev compute done before Bt overwrite
    // ---- stage vlin^T half -> Bt[c][j_local], paired-j b32 writes ----
#pragma unroll
    for (int p = 0; p < 2; p++) {
      int task = tid + p * 256;   // 0..511
      int jp = task & 15;         // j-pair index within half
      int cc = task >> 4;         // c-chunk 0..31 (8 dv each)
      int jl = jp * 2;            // local j (0..30, even)
      int j = kc + jl;            // global j
      int c = cc * 8;             // local col base
      int gcol = n0 + c;
      int w = gcol >> 5, dv = gcol & 31;
      const ushort* vp =
          &vlin[(size_t)(b * 4096 + j * 64 + w) * 256 + hd * 32 + dv];
      u8v v0 = *(const u8v*)vp;
      u8v v1 = *(const u8v*)(vp + 64 * 256);  // next j
#pragma unroll
      for (int q = 0; q < 8; q++) {
        ushort pr[2] = {(ushort)v0[q], (ushort)v1[q]};
        *(uint*)&Bt[(c + q) * 36 + jl] = *(uint*)pr;
      }
    }
    __syncthreads();

    s8v ah_[4], al_[4], bb[4];
#pragma unroll
    for (int mi = 0; mi < 4; mi++) {
      int idx = (mi * 16 + tm) * 68 + kc + quad * 8;
      union { s8v v; unsigned long long u[2]; } th, tl;
      th.u[0] = *(const unsigned long long*)&Ah[idx];
      th.u[1] = *(const unsigned long long*)&Ah[idx + 4];
      tl.u[0] = *(const unsigned long long*)&Al[idx];
      tl.u[1] = *(const unsigned long long*)&Al[idx + 4];
      ah_[mi] = th.v;
      al_[mi] = tl.v;
    }
#pragma unroll
    for (int ni = 0; ni < 4; ni++) {
      int idx = (wn + ni * 16 + tm) * 36 + quad * 8;   // local j = quad*8
      union { s8v v; unsigned long long u[2]; } tb;
      tb.u[0] = *(const unsigned long long*)&Bt[idx];
      tb.u[1] = *(const unsigned long long*)&Bt[idx + 4];
      bb[ni] = tb.v;
    }
#pragma unroll
    for (int mi = 0; mi < 4; mi++)
#pragma unroll
      for (int ni = 0; ni < 4; ni++) {
        acc[mi][ni] = __builtin_amdgcn_mfma_f32_16x16x32_bf16(
            ah_[mi], bb[ni], acc[mi][ni], 0, 0, 0);
        acc[mi][ni] = __builtin_amdgcn_mfma_f32_16x16x32_bf16(
            al_[mi], bb[ni], acc[mi][ni], 0, 0, 0);
      }
  }

  ushort* rp = r1 + (size_t)(b * 8 + hd) * 64 * 2048;
#pragma unroll
  for (int mi = 0; mi < 4; mi++) {
#pragma unroll
    for (int ni = 0; ni < 4; ni++) {
      int col = n0 + wn + ni * 16 + tm;
#pragma unroll
      for (int r = 0; r < 4; r++) {
        int row = mi * 16 + quad * 4 + r;
        rp[(size_t)row * 2048 + col] = f2bf(acc[mi][ni][r]);
      }
    }
  }
}

// ---------------------------------------------------------------------------
// K5b (MFMA): yT[(b*4096+h*64+w')][hd*32+dv]
//               = sum_w r1[b,hd,h,w*32+dv] * attnw[w][w']
// As is K-SPLIT: only 32 of 64 w staged at a time (per-h [32dv][36], 18.5KB)
// -> total LDS 35.9KB (was 52.3) -> 4 blocks/CU (was 3).
// ---------------------------------------------------------------------------
__global__ __launch_bounds__(256) void k_rw(const ushort* __restrict__ r1,
                                            const float* __restrict__ attnw,
                                            ushort* __restrict__ yT) {
  // per-h stride: 32*36 + 4 = 1156 ushorts (2312B, 8B-aligned per h)
  __shared__ __align__(16) ushort As[8 * 1156];   // 18496 B (w-half)
  __shared__ __align__(16) ushort Wh[64 * 68];    //  8704 B  (hi) [w'][w]
  __shared__ __align__(16) ushort Wl[64 * 68];    //  8704 B  (lo)

  int bx = blockIdx.x;
  int ht = bx & 7, hd = (bx >> 3) & 7, b = bx >> 6;
  int tid = threadIdx.x;
  int lane = tid & 63, wave = tid >> 6;
  int tm = lane & 15, quad = lane >> 4;
  int h0 = wave * 2;

  // ---- stage attnw -> Ws[w'][w] transposed, bf16 hi/lo split (full w) ----
  {
    const float* ap = attnw + (size_t)(b * 8 + hd) * 4096;
#pragma unroll
    for (int p = 0; p < 4; p++) {
      int w = (tid >> 4) + p * 16;
      int wq = (tid & 15) * 4;
      float4 v = *(const float4*)&ap[w * 64 + wq];
      float f_[4] = {v.x, v.y, v.z, v.w};
#pragma unroll
      for (int j = 0; j < 4; j++) {
        ushort hi = f2bf(f_[j]);
        Wh[(wq + j) * 68 + w] = hi;
        Wl[(wq + j) * 68 + w] = f2bf(f_[j] - bf2f(hi));
      }
    }
  }

  f4v acc[4][4] = {};
#pragma unroll
  for (int kc = 0; kc < 64; kc += 32) {
    if (kc) __syncthreads();   // prev compute done before As overwrite
    // ---- stage r1 w-half -> As[h][dv][w_local], paired-w b32 writes ----
    {
      int h = tid >> 5;                // 0..7
      int t = tid & 31;
      const ushort* rp =
          r1 + (size_t)((b * 8 + hd) * 64 + ht * 8 + h) * 2048;
#pragma unroll
      for (int i = 0; i < 2; i++) {
        int chunk = t + 32 * i;        // 0..63
        int wl_ = (chunk >> 2) * 2;    // local even w (0..30)
        int w = kc + wl_;              // global w
        int dv0 = (chunk & 3) * 8;
        u8v v0 = *(const u8v*)&rp[w * 32 + dv0];
        u8v v1 = *(const u8v*)&rp[(w + 1) * 32 + dv0];
#pragma unroll
        for (int j = 0; j < 8; j++) {
          ushort pr[2] = {(ushort)v0[j], (ushort)v1[j]};
          *(uint*)&As[h * 1156 + (dv0 + j) * 36 + wl_] = *(uint*)pr;
        }
      }
    }
    __syncthreads();

    s8v a[4], bh[4], bl[4];
#pragma unroll
    for (int mi = 0; mi < 4; mi++) {
      int h = h0 + (mi >> 1);
      int dv = (mi & 1) * 16 + tm;
      int idx = h * 1156 + dv * 36 + quad * 8;   // local w = quad*8
      union { s8v v; unsigned long long u[2]; } t_;
      t_.u[0] = *(const unsigned long long*)&As[idx];
      t_.u[1] = *(const unsigned long long*)&As[idx + 4];
      a[mi] = t_.v;
    }
#pragma unroll
    for (int ni = 0; ni < 4; ni++) {
      int idx = (ni * 16 + tm) * 68 + kc + quad * 8;
      union { s8v v; unsigned long long u[2]; } th, tl;
      th.u[0] = *(const unsigned long long*)&Wh[idx];
      th.u[1] = *(const unsigned long long*)&Wh[idx + 4];
      tl.u[0] = *(const unsigned long long*)&Wl[idx];
      tl.u[1] = *(const unsigned long long*)&Wl[idx + 4];
      bh[ni] = th.v;
      bl[ni] = tl.v;
    }
#pragma unroll
    for (int mi = 0; mi < 4; mi++)
#pragma unroll
      for (int ni = 0; ni < 4; ni++) {
        acc[mi][ni] = __builtin_amdgcn_mfma_f32_16x16x32_bf16(
            a[mi], bh[ni], acc[mi][ni], 0, 0, 0);
        acc[mi][ni] = __builtin_amdgcn_mfma_f32_16x16x32_bf16(
            a[mi], bl[ni], acc[mi][ni], 0, 0, 0);
      }
  }

#pragma unroll
  for (int mi = 0; mi < 4; mi++) {
    int h = ht * 8 + h0 + (mi >> 1);
    int dv0 = (mi & 1) * 16 + quad * 4;
#pragma unroll
    for (int ni = 0; ni < 4; ni++) {
      int wp = ni * 16 + tm;
      ushort pk[4];
#pragma unroll
      for (int r = 0; r < 4; r++) pk[r] = f2bf(acc[mi][ni][r]);
      *(uint2*)&yT[(size_t)(b * 4096 + h * 64 + wp) * 256 + hd * 32 + dv0] =
          *(uint2*)pk;
    }
  }
}

// ---------------------------------------------------------------------------
// K_out: final GEMM, 128m x 256n, 8 waves (512 thr): full-N reuse (A read
// once) without the acc[4][8] VGPR blowup -- each wave owns a 64x64 quadrant.
// ---------------------------------------------------------------------------
__global__ __launch_bounds__(512) void k_out(const ushort* __restrict__ A,
                                             const ushort* __restrict__ W,
                                             const float* __restrict__ bias,
                                             float* __restrict__ out) {
  __shared__ __align__(16) ushort As[128 * 32];
  __shared__ __align__(16) ushort Bs[256 * 32];

  int m0 = blockIdx.x * 128;
  int tid = threadIdx.x;
  int lane = tid & 63, wave = tid >> 6;      // 8 waves
  int wm = (wave & 1) * 64, wn = (wave >> 1) * 64;
  int tm = lane & 15, quad = lane >> 4;
  int xorv = (tm ^ (tm >> 2)) & 3;
  int srow = lane >> 2;
  int slot = lane & 3;

  const ushort* Abase = A + (size_t)m0 * 256;

  f4v acc[4][4] = {};

  for (int kc = 0; kc < 256; kc += 32) {
    __syncthreads();
    // As: 128 rows, 1 gload16 per wave
    {
      int rb = wave * 16;
      int row = rb + srow;
      int xr = (row ^ (row >> 2)) & 3;
      gload16(&Abase[(size_t)row * 256 + kc + (slot ^ xr) * 8], &As[rb * 32]);
    }
    // Bs: 256 rows, 2 gload16 per wave
#pragma unroll
    for (int it = 0; it < 2; it++) {
      int rb = wave * 16 + it * 128;
      int row = rb + srow;
      int xr = (row ^ (row >> 2)) & 3;
      gload16(&W[(size_t)row * 256 + kc + (slot ^ xr) * 8], &Bs[rb * 32]);
    }
    __syncthreads();

    s8v a[4], bfr[4];
#pragma unroll
    for (int mi = 0; mi < 4; mi++)
      a[mi] = *(const s8v*)&As[(wm + mi * 16 + tm) * 32 + (quad ^ xorv) * 8];
#pragma unroll
    for (int ni = 0; ni < 4; ni++)
      bfr[ni] = *(const s8v*)&Bs[(wn + ni * 16 + tm) * 32 + (quad ^ xorv) * 8];
#pragma unroll
    for (int mi = 0; mi < 4; mi++)
#pragma unroll
      for (int ni = 0; ni < 4; ni++)
        acc[mi][ni] = __builtin_amdgcn_mfma_f32_16x16x32_bf16(
            a[mi], bfr[ni], acc[mi][ni], 0, 0, 0);
  }

  // C/D layout: col = lane&15, row = quad*4 + reg
#pragma unroll
  for (int mi = 0; mi < 4; mi++) {
#pragma unroll
    for (int ni = 0; ni < 4; ni++) {
      int col = wn + ni * 16 + tm;
      float bv = bias[col];
#pragma unroll
      for (int r = 0; r < 4; r++) {
        int row = m0 + wm + mi * 16 + quad * 4 + r;
        out[(size_t)row * 256 + col] = acc[mi][ni][r] + bv;
      }
    }
  }
}

// ---------------------------------------------------------------------------
extern "C" void kernel_launch(void* const* d_in, const int* in_sizes, int n_in,
                              void* d_out, int out_size, void* d_ws,
                              size_t ws_size, hipStream_t stream) {
  const float* x      = (const float*)d_in[0];
  const float* dwqh_w = (const float*)d_in[1];
  const float* dwqh_b = (const float*)d_in[2];
  const float* fcqh_w = (const float*)d_in[3];
  const float* fcqh_b = (const float*)d_in[4];
  const float* dwkh_w = (const float*)d_in[5];
  const float* dwkh_b = (const float*)d_in[6];
  const float* fckh_w = (const float*)d_in[7];
  const float* fckh_b = (const float*)d_in[8];
  const float* Bh     = (const float*)d_in[9];
  const float* dwv_w  = (const float*)d_in[10];
  const float* dwv_b  = (const float*)d_in[11];
  const float* fcv_w  = (const float*)d_in[12];
  const float* fcv_b  = (const float*)d_in[13];
  const float* dwqw_w = (const float*)d_in[14];
  const float* dwqw_b = (const float*)d_in[15];
  const float* fcqw_w = (const float*)d_in[16];
  const float* fcqw_b = (const float*)d_in[17];
  const float* dwkw_w = (const float*)d_in[18];
  const float* dwkw_b = (const float*)d_in[19];
  const float* fckw_w = (const float*)d_in[20];
  const float* fckw_b = (const float*)d_in[21];
  const float* Bw     = (const float*)d_in[22];
  const float* fco_w  = (const float*)d_in[23];
  const float* fco_b  = (const float*)d_in[24];

  char* base = (char*)d_ws;
  ushort* P1 = (ushort*)(base);                  // convV, later r1
  ushort* P2 = (ushort*)(base + 33554432);       // yT
  ushort* P3 = (ushort*)(base + 67108864);       // vlin
  ushort* whl  = (ushort*)(base + 100663296);    // 4 x (hi|lo) 65536 bf16
  ushort* wv_bf = (ushort*)(base + 101711872);   // 2 x 65536 bf16
  float* qhm = (float*)(base + 101974016);
  float* khm = qhm + 262144;
  float* qwm = khm + 262144;
  float* kwm = qwm + 262144;
  float* qhl = kwm + 262144;
  float* khl = qhl + 262144;
  float* qwl = khl + 262144;
  float* kwl = qwl + 262144;
  float* ah  = kwl + 262144;                     // 524288
  float* awt = ah + 524288;                      // 524288
  if (ws_size < 115000000ull) return;

  const float scale = 0.17677669529663687f;  // 32^-0.5

  k_conv<<<5632, 256, 0, stream>>>(x, dwqh_w, dwqh_b, dwkh_w, dwkh_b, dwv_w,
                                   dwv_b, dwqw_w, dwqw_b, dwkw_w, dwkw_b,
                                   fcqh_w, fckh_w, fcqw_w, fckw_w, fcv_w,
                                   fco_w, whl, wv_bf, P1,
                                   qhm, khm, qwm, kwm);
  k_mmv<<<1280, 256, 0, stream>>>(P1, wv_bf, fcv_b, P3,
                                  qhm, khm, qwm, kwm, whl, fcqh_b, fckh_b,
                                  fcqw_b, fckw_b, qhl, khl, qwl, kwl);
  k_attn<<<256, 256, 0, stream>>>(qhl, khl, Bh, ah, qwl, kwl, Bw, awt, scale);
  k_av<<<1024, 256, 0, stream>>>(ah, P3, P1);
  k_rw<<<1024, 256, 0, stream>>>(P1, awt, P2);
  k_out<<<512, 512, 0, stream>>>(P2, wv_bf + 65536, fco_b, (float*)d_out);
}